// Round 5
// baseline (1589.826 us; speedup 1.0000x reference)
//
#include <hip/hip_runtime.h>
#include <cstdint>
#include <cmath>

#define B_ 2
#define T_ 2048
#define C_ 2048
#define H_ 32
#define BT_ (B_ * T_)
#define BTC_ ((size_t)B_ * T_ * C_)
#define L_ 128
#define NC_ 16

typedef __attribute__((ext_vector_type(4))) float f32x4;
typedef __attribute__((ext_vector_type(2))) float f32x2;
typedef __attribute__((ext_vector_type(8))) short bf16x8;
typedef __attribute__((ext_vector_type(4))) unsigned short us4;
typedef __attribute__((ext_vector_type(4))) int i32x4;

__device__ __forceinline__ unsigned short f2bf(float f) {
  union { float f; unsigned int u; } c; c.f = f;
  unsigned int u = c.u;
  return (unsigned short)((u + 0x7FFFu + ((u >> 16) & 1u)) >> 16);
}
__device__ __forceinline__ float bf2f(unsigned short h) {
  union { unsigned int u; float f; } c; c.u = ((unsigned int)h) << 16;
  return c.f;
}
__device__ __forceinline__ float rlane(float v, int lane) {
  return __int_as_float(__builtin_amdgcn_readlane(__float_as_int(v), lane));
}
__device__ __forceinline__ void split4(f32x4 v, us4& h, us4& l) {
  h.x = f2bf(v.x); l.x = f2bf(v.x - bf2f(h.x));
  h.y = f2bf(v.y); l.y = f2bf(v.y - bf2f(h.y));
  h.z = f2bf(v.z); l.z = f2bf(v.z - bf2f(h.z));
  h.w = f2bf(v.w); l.w = f2bf(v.w - bf2f(h.w));
}
// async global->LDS, 16 B per lane; LDS dest = wave-uniform base + lane*16
__device__ __forceinline__ void g2l(const void* g, void* l) {
  __builtin_amdgcn_global_load_lds((const __attribute__((address_space(1))) void*)g,
                                   (__attribute__((address_space(3))) void*)l, 16, 0, 0);
}

// ---------------- token shift + mixes: r/k/v as bf16 hi+lo pairs, w/a/g bf16 ----------------
__global__ __launch_bounds__(256) void k_mix(
    const float* __restrict__ x, const float* __restrict__ shift,
    const float* __restrict__ m_r, const float* __restrict__ m_w,
    const float* __restrict__ m_k, const float* __restrict__ m_v,
    const float* __restrict__ m_a, const float* __restrict__ m_g,
    unsigned short* __restrict__ r_h, unsigned short* __restrict__ r_l,
    unsigned short* __restrict__ k_h, unsigned short* __restrict__ k_l,
    unsigned short* __restrict__ v_h, unsigned short* __restrict__ v_l,
    unsigned short* __restrict__ o_w, unsigned short* __restrict__ o_a,
    unsigned short* __restrict__ o_g,
    float* __restrict__ xlast) {
  size_t i4 = ((size_t)blockIdx.x * 256 + threadIdx.x) * 4;
  int c = (int)(i4 % C_);
  size_t bt = i4 / C_;
  int t = (int)(bt % T_);
  int b = (int)(bt / T_);
  f32x4 xv = *(const f32x4*)(x + i4);
  f32x4 pv = (t == 0) ? *(const f32x4*)(shift + (size_t)b * C_ + c)
                      : *(const f32x4*)(x + i4 - C_);
  f32x4 dx = pv - xv;
#define MIXHL(mp, oh, ol) { f32x4 mm = *(const f32x4*)(mp + c); f32x4 rr = xv + dx * mm; \
    us4 hh, ll; split4(rr, hh, ll); *(us4*)(oh + i4) = hh; *(us4*)(ol + i4) = ll; }
#define MIXH(mp, oh) { f32x4 mm = *(const f32x4*)(mp + c); f32x4 rr = xv + dx * mm; \
    us4 pk; pk.x = f2bf(rr.x); pk.y = f2bf(rr.y); pk.z = f2bf(rr.z); pk.w = f2bf(rr.w); \
    *(us4*)(oh + i4) = pk; }
  MIXHL(m_r, r_h, r_l) MIXHL(m_k, k_h, k_l) MIXHL(m_v, v_h, v_l)
  MIXH(m_w, o_w) MIXH(m_a, o_a) MIXH(m_g, o_g)
#undef MIXHL
#undef MIXH
  if (t == T_ - 1) *(f32x4*)(xlast + (size_t)b * C_ + c) = xv;
}

// ---------------- f32 [R][Cc] -> bf16 [Cc][R] transpose ----------------
__global__ __launch_bounds__(256) void k_tr(const float* __restrict__ in,
                                            unsigned short* __restrict__ out,
                                            int R, int Cc) {
  __shared__ float tile[32][33];
  int c0 = blockIdx.x * 32, r0 = blockIdx.y * 32;
  int tid = threadIdx.x;
  int rr = tid >> 3, c4 = (tid & 7) * 4;
  f32x4 v = *(const f32x4*)(in + (size_t)(r0 + rr) * Cc + c0 + c4);
  tile[rr][c4] = v.x; tile[rr][c4 + 1] = v.y; tile[rr][c4 + 2] = v.z; tile[rr][c4 + 3] = v.w;
  __syncthreads();
  int cc = tid >> 3, r4 = (tid & 7) * 4;
  us4 o;
  o.x = f2bf(tile[r4][cc]); o.y = f2bf(tile[r4 + 1][cc]);
  o.z = f2bf(tile[r4 + 2][cc]); o.w = f2bf(tile[r4 + 3][cc]);
  *(us4*)(out + (size_t)(c0 + cc) * R + r0 + r4) = o;
}

// ---------------- f32 [R][Cc] -> bf16 hi+lo [Cc][R] split transpose ----------------
__global__ __launch_bounds__(256) void k_trs(const float* __restrict__ in,
                                             unsigned short* __restrict__ oh,
                                             unsigned short* __restrict__ ol,
                                             int R, int Cc) {
  __shared__ float tile[32][33];
  int c0 = blockIdx.x * 32, r0 = blockIdx.y * 32;
  int tid = threadIdx.x;
  int rr = tid >> 3, c4 = (tid & 7) * 4;
  f32x4 v = *(const f32x4*)(in + (size_t)(r0 + rr) * Cc + c0 + c4);
  tile[rr][c4] = v.x; tile[rr][c4 + 1] = v.y; tile[rr][c4 + 2] = v.z; tile[rr][c4 + 3] = v.w;
  __syncthreads();
  int cc = tid >> 3, r4 = (tid & 7) * 4;
  f32x4 w = { tile[r4][cc], tile[r4 + 1][cc], tile[r4 + 2][cc], tile[r4 + 3][cc] };
  us4 h, l; split4(w, h, l);
  size_t o = (size_t)(c0 + cc) * R + r0 + r4;
  *(us4*)(oh + o) = h; *(us4*)(ol + o) = l;
}

// ---------------- bf16 GEMM: C[M,N] = X[M,K] @ Wt[N,K]^T (global_load_lds staging) ----------------
// XCD-aware bijective block swizzle (T1): all launch grids have nwg % 8 == 0.
__global__ __launch_bounds__(256) void k_gemm(
    const unsigned short* __restrict__ X, const unsigned short* __restrict__ Wt,
    void* __restrict__ out, int M, int N, int K, int mode) {
  __shared__ alignas(16) unsigned short As[128 * 32];
  __shared__ alignas(16) unsigned short Bs[128 * 32];
  const int tid = threadIdx.x;
  const int lane = tid & 63, wave = tid >> 6;
  const int wr = wave >> 1, wc = wave & 1;
  const int lm = lane & 15, lq = lane >> 4;
  const int gx = gridDim.x;
  const int nwg = gx * gridDim.y;
  const int bid = blockIdx.y * gx + blockIdx.x;
  const int sz = (bid & 7) * (nwg >> 3) + (bid >> 3);
  const int m0 = (sz / gx) * 128, n0 = (sz % gx) * 128;
  const int srow = (lane >> 2);
  const int kcol = (lane & 3) * 8;
  f32x4 acc[4][4];
#pragma unroll
  for (int i = 0; i < 4; ++i)
#pragma unroll
    for (int j = 0; j < 4; ++j) acc[i][j] = (f32x4){0.f, 0.f, 0.f, 0.f};

  for (int k0 = 0; k0 < K; k0 += 32) {
#pragma unroll
    for (int p = 0; p < 2; ++p) {
      int row = wave * 32 + p * 16 + srow;
      g2l(X + (size_t)(m0 + row) * K + k0 + kcol, As + (wave * 2 + p) * 512);
      int n = n0 + row; if (n > N - 1) n = N - 1;
      g2l(Wt + (size_t)n * K + k0 + kcol, Bs + (wave * 2 + p) * 512);
    }
    __syncthreads();
    bf16x8 af[4], bfr[4];
#pragma unroll
    for (int i = 0; i < 4; ++i)
      af[i] = *(const bf16x8*)(As + (size_t)(wr * 64 + i * 16 + lm) * 32 + lq * 8);
#pragma unroll
    for (int j = 0; j < 4; ++j)
      bfr[j] = *(const bf16x8*)(Bs + (size_t)(wc * 64 + j * 16 + lm) * 32 + lq * 8);
#pragma unroll
    for (int i = 0; i < 4; ++i)
#pragma unroll
      for (int j = 0; j < 4; ++j)
        acc[i][j] = __builtin_amdgcn_mfma_f32_16x16x32_bf16(af[i], bfr[j], acc[i][j], 0, 0, 0);
    __syncthreads();
  }
#pragma unroll
  for (int i = 0; i < 4; ++i)
#pragma unroll
    for (int j = 0; j < 4; ++j) {
      int n = n0 + wc * 64 + j * 16 + lm;
      if (n >= N) continue;
      int mb = m0 + wr * 64 + i * 16 + lq * 4;
#pragma unroll
      for (int r = 0; r < 4; ++r) {
        float val = acc[i][j][r];
        size_t off = (size_t)(mb + r) * N + n;
        if (mode == 0) {
          ((float*)out)[off] = val;
        } else {
          if (mode == 2) val = tanhf(val);
          else if (mode == 3) val = 1.0f / (1.0f + __expf(-val));
          ((unsigned short*)out)[off] = f2bf(val);
        }
      }
    }
}

// ---------------- split (hi+lo) bf16 GEMM: hh + lh + hl (ll dropped, ~2^-17 rel) ----------------
__global__ __launch_bounds__(256) void k_gemm2(
    const unsigned short* __restrict__ Xh, const unsigned short* __restrict__ Xl, int xlo,
    const unsigned short* __restrict__ Wh, const unsigned short* __restrict__ Wl, int wlo,
    void* __restrict__ out, int M, int N, int K, int mode) {
  __shared__ alignas(16) unsigned short Ah[128 * 32];
  __shared__ alignas(16) unsigned short Al[128 * 32];
  __shared__ alignas(16) unsigned short Bh[128 * 32];
  __shared__ alignas(16) unsigned short Bl[128 * 32];
  const int tid = threadIdx.x;
  const int lane = tid & 63, wave = tid >> 6;
  const int wr = wave >> 1, wc = wave & 1;
  const int lm = lane & 15, lq = lane >> 4;
  const int gx = gridDim.x;
  const int nwg = gx * gridDim.y;
  const int bid = blockIdx.y * gx + blockIdx.x;
  const int sz = (bid & 7) * (nwg >> 3) + (bid >> 3);
  const int m0 = (sz / gx) * 128, n0 = (sz % gx) * 128;
  const int srow = (lane >> 2);
  const int kcol = (lane & 3) * 8;
  f32x4 acc[4][4];
#pragma unroll
  for (int i = 0; i < 4; ++i)
#pragma unroll
    for (int j = 0; j < 4; ++j) acc[i][j] = (f32x4){0.f, 0.f, 0.f, 0.f};

  for (int k0 = 0; k0 < K; k0 += 32) {
#pragma unroll
    for (int p = 0; p < 2; ++p) {
      int row = wave * 32 + p * 16 + srow;
      int off = (wave * 2 + p) * 512;
      size_t ga = (size_t)(m0 + row) * K + k0 + kcol;
      g2l(Xh + ga, Ah + off);
      if (xlo) g2l(Xl + ga, Al + off);
      int n = n0 + row; if (n > N - 1) n = N - 1;
      size_t gb = (size_t)n * K + k0 + kcol;
      g2l(Wh + gb, Bh + off);
      if (wlo) g2l(Wl + gb, Bl + off);
    }
    __syncthreads();
    bf16x8 ah[4], bh[4];
#pragma unroll
    for (int i = 0; i < 4; ++i)
      ah[i] = *(const bf16x8*)(Ah + (size_t)(wr * 64 + i * 16 + lm) * 32 + lq * 8);
#pragma unroll
    for (int j = 0; j < 4; ++j)
      bh[j] = *(const bf16x8*)(Bh + (size_t)(wc * 64 + j * 16 + lm) * 32 + lq * 8);
#pragma unroll
    for (int i = 0; i < 4; ++i)
#pragma unroll
      for (int j = 0; j < 4; ++j)
        acc[i][j] = __builtin_amdgcn_mfma_f32_16x16x32_bf16(ah[i], bh[j], acc[i][j], 0, 0, 0);
    if (xlo) {
      bf16x8 al[4];
#pragma unroll
      for (int i = 0; i < 4; ++i)
        al[i] = *(const bf16x8*)(Al + (size_t)(wr * 64 + i * 16 + lm) * 32 + lq * 8);
#pragma unroll
      for (int i = 0; i < 4; ++i)
#pragma unroll
        for (int j = 0; j < 4; ++j)
          acc[i][j] = __builtin_amdgcn_mfma_f32_16x16x32_bf16(al[i], bh[j], acc[i][j], 0, 0, 0);
    }
    if (wlo) {
      bf16x8 bl[4];
#pragma unroll
      for (int j = 0; j < 4; ++j)
        bl[j] = *(const bf16x8*)(Bl + (size_t)(wc * 64 + j * 16 + lm) * 32 + lq * 8);
#pragma unroll
      for (int i = 0; i < 4; ++i)
#pragma unroll
        for (int j = 0; j < 4; ++j)
          acc[i][j] = __builtin_amdgcn_mfma_f32_16x16x32_bf16(ah[i], bl[j], acc[i][j], 0, 0, 0);
    }
    __syncthreads();
  }
#pragma unroll
  for (int i = 0; i < 4; ++i)
#pragma unroll
    for (int j = 0; j < 4; ++j) {
      int n = n0 + wc * 64 + j * 16 + lm;
      if (n >= N) continue;
      int mb = m0 + wr * 64 + i * 16 + lq * 4;
#pragma unroll
      for (int r = 0; r < 4; ++r) {
        float val = acc[i][j][r];
        size_t off = (size_t)(mb + r) * N + n;
        if (mode == 0) {
          ((float*)out)[off] = val;
        } else {
          if (mode == 2) val = tanhf(val);
          else if (mode == 3) val = 1.0f / (1.0f + __expf(-val));
          ((unsigned short*)out)[off] = f2bf(val);
        }
      }
    }
}

// ---------------- pre-scan fused elementwise ----------------
__global__ __launch_bounds__(256) void k_pre(
    const float* __restrict__ rp, const float* __restrict__ kp, float* __restrict__ vp,
    const unsigned short* __restrict__ ww, const unsigned short* __restrict__ aa,
    const unsigned short* __restrict__ vv,
    const float* __restrict__ vfirst,
    const float* __restrict__ w0, const float* __restrict__ a0, const float* __restrict__ v0,
    const float* __restrict__ kkc, const float* __restrict__ kac,
    const float* __restrict__ rkw,
    unsigned short* __restrict__ rb, unsigned short* __restrict__ wb,
    unsigned short* __restrict__ kb, unsigned short* __restrict__ vb,
    unsigned short* __restrict__ ab, unsigned short* __restrict__ bb,
    float* __restrict__ dp) {
  int gw = blockIdx.x * 4 + (threadIdx.x >> 6);
  int l = threadIdx.x & 63;
  int h = gw & (H_ - 1);
  size_t bt = (size_t)(gw >> 5);
  size_t idx = bt * C_ + h * 64 + l;
  int c = h * 64 + l;
  float rf = rp[idx], kf = kp[idx], vr = vp[idx];
  float z = -(w0[c] + bf2f(ww[idx]));
  float sp = (z > 15.f) ? z : log1pf(__expf(z));
  float wv = -sp - 0.5f;
  float ag = 1.f / (1.f + __expf(-(a0[c] + bf2f(aa[idx]))));
  float sv = 1.f / (1.f + __expf(-(v0[c] + bf2f(vv[idx]))));
  float vf = vr + (vfirst[idx] - vr) * sv;
  float kkv = kf * kkc[c];
  float ss = kkv * kkv;
#pragma unroll
  for (int m = 1; m < 64; m <<= 1) ss += __shfl_xor(ss, m);
  float nrm = fmaxf(sqrtf(ss), 1e-12f);
  float kkn = kkv / nrm;
  float ks = kf * (1.f + (ag - 1.f) * kac[c]);
  vp[idx] = vf;
  float bon = rf * ks * rkw[c];
#pragma unroll
  for (int m = 1; m < 64; m <<= 1) bon += __shfl_xor(bon, m);
  if (l == 0) dp[bt * H_ + h] = bon;
  rb[idx] = f2bf(rf); wb[idx] = f2bf(wv); kb[idx] = f2bf(ks);
  vb[idx] = f2bf(vf); ab[idx] = f2bf(-kkn); bb[idx] = f2bf(kkn * ag);
}

// ================= chunk-parallel scan: TWO INDEPENDENT WAVES PER CHUNK =================
// Role-split (P-chain wave / U-chain wave) as before, but the per-k scalar
// broadcasts go through LDS broadcast reads instead of v_readlane:
// each wave stages its step-t row {ew,b,r,a,(k)}[j] with ONE ds_write_b128
// (own private region, same-wave ordering -> no barrier), then the k-loop
// reads 4 scalars per k with ONE uniform-address ds_read_b128 (broadcast,
// conflict-free). VALU ops per k drop ~2x; DS ops co-issue with the sibling
// wave's VALU. Arithmetic is bit-identical to round 3/4 (absmax canary).
__global__ __launch_bounds__(128) void k_scanP(
    const unsigned short* __restrict__ rb,
    const unsigned short* __restrict__ wb, const unsigned short* __restrict__ kb,
    const unsigned short* __restrict__ vb, const unsigned short* __restrict__ ab,
    const unsigned short* __restrict__ bb,
    float* __restrict__ Pg, float* __restrict__ Ug,
    unsigned short* __restrict__ Zg, float* __restrict__ o) {
  const int blk = blockIdx.x;
  const int c = blk & (NC_ - 1), bh = blk >> 4;
  const int b = bh >> 5, h = bh & (H_ - 1);
  const int l = threadIdx.x & 63;
  const int role = __builtin_amdgcn_readfirstlane(threadIdx.x >> 6);
  __shared__ float st[2][64][8];
  float (*S8)[8] = st[role];
  size_t base = (size_t)b * ((size_t)T_ * C_) + (size_t)(c * L_) * C_ + h * 64 + l;
  if (role == 0) {
    // ---------- P / transition wave: needs w, b, a, r ----------
    size_t zbase = (size_t)blk * 8192;
    float P[64];
#pragma unroll
    for (int k = 0; k < 64; ++k) P[k] = (k == l) ? 1.f : 0.f;
    float pw[4], pb[4], pa[4], pr[4];
#pragma unroll
    for (int s = 0; s < 4; ++s) {
      size_t a_ = base + (size_t)s * C_;
      pw[s] = bf2f(wb[a_]); pb[s] = bf2f(bb[a_]); pr[s] = bf2f(rb[a_]);
      pa[s] = bf2f(ab[base + (size_t)(s + 1) * C_]);  // a one step ahead
    }
    float saP = bf2f(ab[base]);  // t=0: A=I -> saP = a_0[l]
    for (int t0 = 0; t0 < L_; t0 += 4) {
#pragma unroll
      for (int u = 0; u < 4; ++u) {
        const int t = t0 + u;
        float wl = pw[u], bl = pb[u], al = pa[u], rl_ = pr[u];
        if (t + 4 < L_) {
          size_t a_ = base + (size_t)(t + 4) * C_;
          pw[u] = bf2f(wb[a_]); pb[u] = bf2f(bb[a_]); pr[u] = bf2f(rb[a_]);
          int ta = t + 5; if (ta > L_ - 1) ta = L_ - 1;  // clamped value feeds discarded sa_L
          pa[u] = bf2f(ab[base + (size_t)ta * C_]);
        }
        float ew = exp2f(wl * 1.4426950408889634f);
        // stage the broadcast row for this step (own region, no barrier)
        *(f32x4*)(&S8[l][0]) = (f32x4){ew, bl, rl_, al};
        float zz0 = 0.f, zz1 = 0.f, zz2 = 0.f, zz3 = 0.f;
        float qp0 = 0.f, qp1 = 0.f, qp2 = 0.f, qp3 = 0.f;
#pragma unroll
        for (int k = 0; k < 64; k += 4) {
#define PSTEP(kk, ZZ, QP)                                                \
          {                                                              \
            f32x4 s4 = *(const f32x4*)(&S8[kk][0]);                      \
            float Pn = fmaf(P[kk], s4.x, s4.y * saP);                    \
            P[kk] = Pn;                                                  \
            ZZ = fmaf(s4.z, Pn, ZZ); QP = fmaf(s4.w, Pn, QP);            \
          }
          PSTEP(k,     zz0, qp0)
          PSTEP(k + 1, zz1, qp1)
          PSTEP(k + 2, zz2, qp2)
          PSTEP(k + 3, zz3, qp3)
#undef PSTEP
        }
        Zg[zbase + t * 64 + l] = f2bf((zz0 + zz1) + (zz2 + zz3));
        saP = (qp0 + qp1) + (qp2 + qp3);
      }
    }
    size_t pb_ = (size_t)blk * 4096;
#pragma unroll
    for (int k4 = 0; k4 < 64; k4 += 4) {
      f32x4 pv4 = { P[k4], P[k4 + 1], P[k4 + 2], P[k4 + 3] };
      *(f32x4*)(Pg + pb_ + (size_t)l * 64 + k4) = pv4;
    }
  } else {
    // ---------- U wave: needs w, b, k, v, a, r ----------
    float U[64];
#pragma unroll
    for (int k = 0; k < 64; ++k) U[k] = 0.f;
    float pw[4], pb[4], pk[4], pv[4], pa[4], pr[4];
#pragma unroll
    for (int s = 0; s < 4; ++s) {
      size_t a_ = base + (size_t)s * C_;
      pw[s] = bf2f(wb[a_]); pb[s] = bf2f(bb[a_]); pk[s] = bf2f(kb[a_]);
      pv[s] = bf2f(vb[a_]); pr[s] = bf2f(rb[a_]);
      pa[s] = bf2f(ab[base + (size_t)(s + 1) * C_]);
    }
    float saU = 0.f;
    for (int t0 = 0; t0 < L_; t0 += 4) {
#pragma unroll
      for (int u = 0; u < 4; ++u) {
        const int t = t0 + u;
        float wl = pw[u], bl = pb[u], kl = pk[u], vl = pv[u], al = pa[u], rl_ = pr[u];
        if (t + 4 < L_) {
          size_t a_ = base + (size_t)(t + 4) * C_;
          pw[u] = bf2f(wb[a_]); pb[u] = bf2f(bb[a_]); pk[u] = bf2f(kb[a_]);
          pv[u] = bf2f(vb[a_]); pr[u] = bf2f(rb[a_]);
          int ta = t + 5; if (ta > L_ - 1) ta = L_ - 1;
          pa[u] = bf2f(ab[base + (size_t)ta * C_]);
        }
        float ew = exp2f(wl * 1.4426950408889634f);
        *(f32x4*)(&S8[l][0]) = (f32x4){ew, bl, rl_, al};
        S8[l][4] = kl;
        float yy0 = 0.f, yy1 = 0.f, yy2 = 0.f, yy3 = 0.f;
        float qu0 = 0.f, qu1 = 0.f, qu2 = 0.f, qu3 = 0.f;
#pragma unroll
        for (int k = 0; k < 64; k += 4) {
#define USTEP(kk, YY, QU)                                                \
          {                                                              \
            f32x4 s4 = *(const f32x4*)(&S8[kk][0]);                      \
            float sk = S8[kk][4];                                        \
            float Un = fmaf(U[kk], s4.x, fmaf(s4.y, saU, sk * vl));      \
            U[kk] = Un;                                                  \
            YY = fmaf(s4.z, Un, YY); QU = fmaf(s4.w, Un, QU);            \
          }
          USTEP(k,     yy0, qu0)
          USTEP(k + 1, yy1, qu1)
          USTEP(k + 2, yy2, qu2)
          USTEP(k + 3, yy3, qu3)
#undef USTEP
        }
        o[base + (size_t)t * C_] = (yy0 + yy1) + (yy2 + yy3);
        saU = (qu0 + qu1) + (qu2 + qu3);
      }
    }
    size_t pb_ = (size_t)blk * 4096;
#pragma unroll
    for (int k = 0; k < 64; ++k) Ug[pb_ + (size_t)k * 64 + l] = U[k];
  }
}

__global__ __launch_bounds__(256) void k_scanC(
    const float* __restrict__ Pg, const float* __restrict__ Ug,
    const float* __restrict__ s0, float* __restrict__ Scg, float* __restrict__ sout) {
  const int bh = blockIdx.x;
  const int l = threadIdx.x & 63;
  const int kg = __builtin_amdgcn_readfirstlane(threadIdx.x >> 6);
  const int kg16 = kg * 16;
  const int tid = threadIdx.x;
  __shared__ float Sb[4096];
#pragma unroll
  for (int q = 0; q < 4; ++q) {
    int e = tid * 16 + q * 4;
    *(f32x4*)(Sb + e) = *(const f32x4*)(s0 + (size_t)bh * 4096 + e);
  }
  __syncthreads();
  for (int c = 0; c < NC_; ++c) {
    size_t cb = ((size_t)bh * NC_ + c) * 4096;
#pragma unroll
    for (int q = 0; q < 4; ++q) {
      int e = tid * 16 + q * 4;
      *(f32x4*)(Scg + cb + e) = *(const f32x4*)(Sb + e);
    }
    const float* Pt = Pg + cb;
    const float* Uc = Ug + cb;
    float acc[16];
#pragma unroll
    for (int i = 0; i < 16; ++i) acc[i] = Uc[(size_t)(kg16 + i) * 64 + l];
    for (int j = 0; j < 64; ++j) {
      float s = Sb[j * 64 + l];
#pragma unroll
      for (int i = 0; i < 16; ++i) acc[i] = fmaf(Pt[j * 64 + kg16 + i], s, acc[i]);
    }
    __syncthreads();
#pragma unroll
    for (int i = 0; i < 16; ++i) Sb[(kg16 + i) * 64 + l] = acc[i];
    __syncthreads();
  }
#pragma unroll
  for (int q = 0; q < 4; ++q) {
    int e = tid * 16 + q * 4;
    *(f32x4*)(sout + (size_t)bh * 4096 + e) = *(const f32x4*)(Sb + e);
  }
}

// ---------------- apply chunk-start state: o += Z @ S0 (per chunk) ----------------
__global__ __launch_bounds__(256) void k_scanO(
    const unsigned short* __restrict__ Zg, const float* __restrict__ Scg,
    float* __restrict__ o) {
  const int blk = blockIdx.x;
  const int c = blk & (NC_ - 1), bh = blk >> 4;
  const int b = bh >> 5, h = bh & (H_ - 1);
  const int l = threadIdx.x & 63;
  const int w = threadIdx.x >> 6;
  float S[64];
  const float* Sp = Scg + (size_t)blk * 4096 + l;
#pragma unroll
  for (int k = 0; k < 64; ++k) S[k] = Sp[(size_t)k * 64];
  size_t zb = (size_t)blk * 8192;
  size_t ob = (size_t)b * ((size_t)T_ * C_) + (size_t)(c * L_) * C_ + h * 64 + l;
  for (int tt = 0; tt < 32; ++tt) {
    int t = w * 32 + tt;
    float zv = bf2f(Zg[zb + t * 64 + l]);  // lane l holds z_t[l]
    float a0_ = 0.f, a1_ = 0.f, a2_ = 0.f, a3_ = 0.f;
#pragma unroll
    for (int k = 0; k < 64; k += 4) {
      a0_ = fmaf(rlane(zv, k), S[k], a0_);
      a1_ = fmaf(rlane(zv, k + 1), S[k + 1], a1_);
      a2_ = fmaf(rlane(zv, k + 2), S[k + 2], a2_);
      a3_ = fmaf(rlane(zv, k + 3), S[k + 3], a3_);
    }
    o[ob + (size_t)t * C_] += (a0_ + a1_) + (a2_ + a3_);
  }
}

// ---------------- post-scan: GroupNorm + bonus + *g -> bf16 ----------------
__global__ __launch_bounds__(256) void k_post(
    const float* __restrict__ o, const float* __restrict__ vp, const float* __restrict__ gp,
    const float* __restrict__ dp,
    const float* __restrict__ lnw, const float* __restrict__ lnb,
    unsigned short* __restrict__ z) {
  int gw = blockIdx.x * 4 + (threadIdx.x >> 6);
  int l = threadIdx.x & 63;
  int h = gw & (H_ - 1);
  size_t bt = (size_t)(gw >> 5);
  size_t idx = bt * C_ + h * 64 + l;
  int c = h * 64 + l;
  float ov = o[idx];
  float s1 = ov;
#pragma unroll
  for (int m = 1; m < 64; m <<= 1) s1 += __shfl_xor(s1, m);
  float mu = s1 * (1.f / 64.f);
  float d = ov - mu;
  float s2 = d * d;
#pragma unroll
  for (int m = 1; m < 64; m <<= 1) s2 += __shfl_xor(s2, m);
  float var = s2 * (1.f / 64.f);
  float y = d * rsqrtf(var + 6.4e-4f);
  y = y * lnw[c] + lnb[c];
  y = fmaf(dp[bt * H_ + h], vp[idx], y);
  z[idx] = f2bf(y * gp[idx]);
}

extern "C" void kernel_launch(void* const* d_in, const int* in_sizes, int n_in,
                              void* d_out, int out_size, void* d_ws, size_t ws_size,
                              hipStream_t stream) {
  const float* x      = (const float*)d_in[0];
  const float* shift  = (const float*)d_in[1];
  const float* wkv    = (const float*)d_in[2];
  const float* vfirst = (const float*)d_in[3];
  const float* x_r    = (const float*)d_in[4];
  const float* x_w    = (const float*)d_in[5];
  const float* x_k    = (const float*)d_in[6];
  const float* x_v    = (const float*)d_in[7];
  const float* x_a    = (const float*)d_in[8];
  const float* x_g    = (const float*)d_in[9];
  const float* w0     = (const float*)d_in[10];
  const float* w1     = (const float*)d_in[11];
  const float* w2     = (const float*)d_in[12];
  const float* a0     = (const float*)d_in[13];
  const float* a1     = (const float*)d_in[14];
  const float* a2     = (const float*)d_in[15];
  const float* v0     = (const float*)d_in[16];
  const float* v1     = (const float*)d_in[17];
  const float* v2     = (const float*)d_in[18];
  const float* g1     = (const float*)d_in[19];
  const float* g2     = (const float*)d_in[20];
  const float* k_k    = (const float*)d_in[21];
  const float* k_a    = (const float*)d_in[22];
  const float* r_k    = (const float*)d_in[23];
  const float* W_r    = (const float*)d_in[24];
  const float* W_k    = (const float*)d_in[25];
  const float* W_v    = (const float*)d_in[26];
  const float* W_o    = (const float*)d_in[27];
  const float* ln_w   = (const float*)d_in[28];
  const float* ln_b   = (const float*)d_in[29];

  // ---- workspace plan: ~213 MiB (footprint identical to passing version) ----
  char* wp = (char*)d_ws;
  auto alloc = [&](size_t bytes) { char* p = wp; wp += (bytes + 255) & ~(size_t)255; return p; };
  const size_t SB = BTC_ * 2;
  const size_t SF = BTC_ * 4;

  unsigned short* w1t = (unsigned short*)alloc((size_t)C_ * 64 * 2);
  unsigned short* w2t = (unsigned short*)alloc((size_t)C_ * 64 * 2);
  unsigned short* a1t = (unsigned short*)alloc((size_t)C_ * 64 * 2);
  unsigned short* a2t = (unsigned short*)alloc((size_t)C_ * 64 * 2);
  unsigned short* v1t = (unsigned short*)alloc((size_t)C_ * 32 * 2);
  unsigned short* v2t = (unsigned short*)alloc((size_t)C_ * 32 * 2);
  unsigned short* g1t = (unsigned short*)alloc((size_t)C_ * 128 * 2);
  unsigned short* g2t = (unsigned short*)alloc((size_t)C_ * 128 * 2);
  unsigned short* hw  = (unsigned short*)alloc((size_t)BT_ * 64 * 2);
  unsigned short* ha  = (unsigned short*)alloc((size_t)BT_ * 64 * 2);
  unsigned short* hv  = (unsigned short*)alloc((size_t)BT_ * 32 * 2);
  unsigned short* hg  = (unsigned short*)alloc((size_t)BT_ * 128 * 2);
  unsigned short* Wt2 = (unsigned short*)alloc((size_t)C_ * C_ * 2 * 2); // hi|lo; later Zg (bf16)
  float* dp           = (float*)alloc((size_t)BT_ * H_ * 4);
  unsigned short* xw  = (unsigned short*)alloc(SB);      // mix-w -> wb -> Scg (f32)
  unsigned short* xa  = (unsigned short*)alloc(SB);
  unsigned short* xg  = (unsigned short*)alloc(SB);
  unsigned short* xr2 = (unsigned short*)alloc(2 * SB); // -> kbuf f32 -> Pg|Ug -> zbuf
  unsigned short* xk2 = (unsigned short*)alloc(2 * SB); // -> vbuf f32
  unsigned short* xv2 = (unsigned short*)alloc(2 * SB); // -> scan rb|kb
  float* rbuf         = (float*)alloc(SF);              // r f32 -> g f32
  unsigned short* vbb = (unsigned short*)alloc(SB);

  unsigned short* Wh = Wt2;
  unsigned short* Wl = Wt2 + (size_t)C_ * C_;
  unsigned short* xr_h = xr2, *xr_l = xr2 + BTC_;
  unsigned short* xk_h = xk2, *xk_l = xk2 + BTC_;
  unsigned short* xv_h = xv2, *xv_l = xv2 + BTC_;
  float* kbuf = (float*)xr2;
  float* vbuf = (float*)xk2;
  unsigned short* rb = xv2;
  unsigned short* kb = xv2 + BTC_;
  float* gfull = rbuf;
  unsigned short* zbuf = (unsigned short*)xr2;
  float* Pg  = (float*)xr2;
  float* Ug  = Pg + (size_t)1024 * 4096;
  unsigned short* zg = Wt2;          // bf16 z-coefficients, 16 MiB (Wt2 dead here)
  float* Scg = (float*)xw;           // chunk-start states, 16 MiB (wb dead after scanP)

  float* outp  = (float*)d_out;
  float* xlast = outp + BTC_;
  float* soutp = outp + BTC_ + (size_t)B_ * C_;
  float* obuf  = outp;

  auto tr = [&](const float* in, unsigned short* out, int R, int Cc) {
    k_tr<<<dim3(Cc / 32, R / 32), 256, 0, stream>>>(in, out, R, Cc);
  };
  auto gemm = [&](const unsigned short* X, const unsigned short* Wtp, void* out,
                  int M, int N, int K, int mode) {
    k_gemm<<<dim3((N + 127) / 128, M / 128), 256, 0, stream>>>(X, Wtp, out, M, N, K, mode);
  };
  auto gemm2 = [&](const unsigned short* Xh_, const unsigned short* Xl_, int xlo,
                   const unsigned short* Wh_, const unsigned short* Wl_, int wlo,
                   void* out, int M, int N, int K, int mode) {
    k_gemm2<<<dim3((N + 127) / 128, M / 128), 256, 0, stream>>>(Xh_, Xl_, xlo, Wh_, Wl_, wlo,
                                                                out, M, N, K, mode);
  };

  k_mix<<<(int)(BTC_ / 4 / 256), 256, 0, stream>>>(x, shift, x_r, x_w, x_k, x_v, x_a, x_g,
                                                   xr_h, xr_l, xk_h, xk_l, xv_h, xv_l,
                                                   xw, xa, xg, xlast);
  tr(w1, w1t, C_, 64);  tr(w2, w2t, 64, C_);
  tr(a1, a1t, C_, 64);  tr(a2, a2t, 64, C_);
  tr(v1, v1t, C_, 32);  tr(v2, v2t, 32, C_);
  tr(g1, g1t, C_, 128); tr(g2, g2t, 128, C_);

  // LoRA stage 1
  gemm(xw, w1t, hw, BT_, 64, C_, 2);
  gemm(xa, a1t, ha, BT_, 64, C_, 1);
  gemm2(xv_h, xv_l, 1, v1t, nullptr, 0, hv, BT_, 32, C_, 1);
  gemm(xg, g1t, hg, BT_, 128, C_, 3);

  // big projections, split precision (hh + lh + hl)
  k_trs<<<dim3(C_ / 32, C_ / 32), 256, 0, stream>>>(W_r, Wh, Wl, C_, C_);
  gemm2(xr_h, xr_l, 1, Wh, Wl, 1, rbuf, BT_, C_, C_, 0);
  k_trs<<<dim3(C_ / 32, C_ / 32), 256, 0, stream>>>(W_k, Wh, Wl, C_, C_);
  gemm2(xk_h, xk_l, 1, Wh, Wl, 1, kbuf, BT_, C_, C_, 0);
  k_trs<<<dim3(C_ / 32, C_ / 32), 256, 0, stream>>>(W_v, Wh, Wl, C_, C_);
  gemm2(xv_h, xv_l, 1, Wh, Wl, 1, vbuf, BT_, C_, C_, 0);

  // LoRA stage 2 into dead mix buffers
  gemm(hw, w2t, xw, BT_, C_, 64, 1);
  gemm(ha, a2t, xa, BT_, C_, 64, 1);
  gemm(hv, v2t, xg, BT_, C_, 32, 1);

  k_pre<<<BT_ * H_ / 4, 256, 0, stream>>>(rbuf, kbuf, vbuf, xw, xa, xg, vfirst,
                                          w0, a0, v0, k_k, k_a, r_k,
                                          rb, xw, kb, vbb, xa, xg, dp);

  gemm(hg, g2t, gfull, BT_, C_, 128, 0);

  // chunk-parallel scan: P/U/z/y in one pass, combine, then apply S0 (no replay)
  k_scanP<<<B_ * H_ * NC_, 128, 0, stream>>>(rb, xw, kb, vbb, xa, xg, Pg, Ug, zg, obuf);
  k_scanC<<<B_ * H_, 256, 0, stream>>>(Pg, Ug, wkv, Scg, soutp);
  k_scanO<<<B_ * H_ * NC_, 256, 0, stream>>>(zg, Scg, obuf);

  k_post<<<BT_ * H_ / 4, 256, 0, stream>>>(obuf, vbuf, gfull, dp, ln_w, ln_b, zbuf);

  tr(W_o, Wh, C_, C_);
  gemm(zbuf, Wh, outp, BT_, C_, C_, 0);
}

// Round 6
// 1379.200 us; speedup vs baseline: 1.1527x; 1.1527x over previous
//
#include <hip/hip_runtime.h>
#include <cstdint>
#include <cmath>

#define B_ 2
#define T_ 2048
#define C_ 2048
#define H_ 32
#define BT_ (B_ * T_)
#define BTC_ ((size_t)B_ * T_ * C_)
#define L_ 64
#define NC_ 32

typedef __attribute__((ext_vector_type(4))) float f32x4;
typedef __attribute__((ext_vector_type(2))) float f32x2;
typedef __attribute__((ext_vector_type(8))) short bf16x8;
typedef __attribute__((ext_vector_type(4))) unsigned short us4;
typedef __attribute__((ext_vector_type(4))) int i32x4;

__device__ __forceinline__ unsigned short f2bf(float f) {
  union { float f; unsigned int u; } c; c.f = f;
  unsigned int u = c.u;
  return (unsigned short)((u + 0x7FFFu + ((u >> 16) & 1u)) >> 16);
}
__device__ __forceinline__ float bf2f(unsigned short h) {
  union { unsigned int u; float f; } c; c.u = ((unsigned int)h) << 16;
  return c.f;
}
__device__ __forceinline__ float rlane(float v, int lane) {
  return __int_as_float(__builtin_amdgcn_readlane(__float_as_int(v), lane));
}
__device__ __forceinline__ void split4(f32x4 v, us4& h, us4& l) {
  h.x = f2bf(v.x); l.x = f2bf(v.x - bf2f(h.x));
  h.y = f2bf(v.y); l.y = f2bf(v.y - bf2f(h.y));
  h.z = f2bf(v.z); l.z = f2bf(v.z - bf2f(h.z));
  h.w = f2bf(v.w); l.w = f2bf(v.w - bf2f(h.w));
}
// async global->LDS, 16 B per lane; LDS dest = wave-uniform base + lane*16
__device__ __forceinline__ void g2l(const void* g, void* l) {
  __builtin_amdgcn_global_load_lds((const __attribute__((address_space(1))) void*)g,
                                   (__attribute__((address_space(3))) void*)l, 16, 0, 0);
}

// ---------------- token shift + mixes: r/k/v as bf16 hi+lo pairs, w/a/g bf16 ----------------
__global__ __launch_bounds__(256) void k_mix(
    const float* __restrict__ x, const float* __restrict__ shift,
    const float* __restrict__ m_r, const float* __restrict__ m_w,
    const float* __restrict__ m_k, const float* __restrict__ m_v,
    const float* __restrict__ m_a, const float* __restrict__ m_g,
    unsigned short* __restrict__ r_h, unsigned short* __restrict__ r_l,
    unsigned short* __restrict__ k_h, unsigned short* __restrict__ k_l,
    unsigned short* __restrict__ v_h, unsigned short* __restrict__ v_l,
    unsigned short* __restrict__ o_w, unsigned short* __restrict__ o_a,
    unsigned short* __restrict__ o_g,
    float* __restrict__ xlast) {
  size_t i4 = ((size_t)blockIdx.x * 256 + threadIdx.x) * 4;
  int c = (int)(i4 % C_);
  size_t bt = i4 / C_;
  int t = (int)(bt % T_);
  int b = (int)(bt / T_);
  f32x4 xv = *(const f32x4*)(x + i4);
  f32x4 pv = (t == 0) ? *(const f32x4*)(shift + (size_t)b * C_ + c)
                      : *(const f32x4*)(x + i4 - C_);
  f32x4 dx = pv - xv;
#define MIXHL(mp, oh, ol) { f32x4 mm = *(const f32x4*)(mp + c); f32x4 rr = xv + dx * mm; \
    us4 hh, ll; split4(rr, hh, ll); *(us4*)(oh + i4) = hh; *(us4*)(ol + i4) = ll; }
#define MIXH(mp, oh) { f32x4 mm = *(const f32x4*)(mp + c); f32x4 rr = xv + dx * mm; \
    us4 pk; pk.x = f2bf(rr.x); pk.y = f2bf(rr.y); pk.z = f2bf(rr.z); pk.w = f2bf(rr.w); \
    *(us4*)(oh + i4) = pk; }
  MIXHL(m_r, r_h, r_l) MIXHL(m_k, k_h, k_l) MIXHL(m_v, v_h, v_l)
  MIXH(m_w, o_w) MIXH(m_a, o_a) MIXH(m_g, o_g)
#undef MIXHL
#undef MIXH
  if (t == T_ - 1) *(f32x4*)(xlast + (size_t)b * C_ + c) = xv;
}

// ---------------- f32 [R][Cc] -> bf16 [Cc][R] transpose ----------------
__global__ __launch_bounds__(256) void k_tr(const float* __restrict__ in,
                                            unsigned short* __restrict__ out,
                                            int R, int Cc) {
  __shared__ float tile[32][33];
  int c0 = blockIdx.x * 32, r0 = blockIdx.y * 32;
  int tid = threadIdx.x;
  int rr = tid >> 3, c4 = (tid & 7) * 4;
  f32x4 v = *(const f32x4*)(in + (size_t)(r0 + rr) * Cc + c0 + c4);
  tile[rr][c4] = v.x; tile[rr][c4 + 1] = v.y; tile[rr][c4 + 2] = v.z; tile[rr][c4 + 3] = v.w;
  __syncthreads();
  int cc = tid >> 3, r4 = (tid & 7) * 4;
  us4 o;
  o.x = f2bf(tile[r4][cc]); o.y = f2bf(tile[r4 + 1][cc]);
  o.z = f2bf(tile[r4 + 2][cc]); o.w = f2bf(tile[r4 + 3][cc]);
  *(us4*)(out + (size_t)(c0 + cc) * R + r0 + r4) = o;
}

// ---------------- f32 [R][Cc] -> bf16 hi+lo [Cc][R] split transpose ----------------
__global__ __launch_bounds__(256) void k_trs(const float* __restrict__ in,
                                             unsigned short* __restrict__ oh,
                                             unsigned short* __restrict__ ol,
                                             int R, int Cc) {
  __shared__ float tile[32][33];
  int c0 = blockIdx.x * 32, r0 = blockIdx.y * 32;
  int tid = threadIdx.x;
  int rr = tid >> 3, c4 = (tid & 7) * 4;
  f32x4 v = *(const f32x4*)(in + (size_t)(r0 + rr) * Cc + c0 + c4);
  tile[rr][c4] = v.x; tile[rr][c4 + 1] = v.y; tile[rr][c4 + 2] = v.z; tile[rr][c4 + 3] = v.w;
  __syncthreads();
  int cc = tid >> 3, r4 = (tid & 7) * 4;
  f32x4 w = { tile[r4][cc], tile[r4 + 1][cc], tile[r4 + 2][cc], tile[r4 + 3][cc] };
  us4 h, l; split4(w, h, l);
  size_t o = (size_t)(c0 + cc) * R + r0 + r4;
  *(us4*)(oh + o) = h; *(us4*)(ol + o) = l;
}

// ---------------- bf16 GEMM: C[M,N] = X[M,K] @ Wt[N,K]^T (global_load_lds staging) ----------------
// XCD-aware bijective block swizzle (T1): all launch grids have nwg % 8 == 0.
__global__ __launch_bounds__(256) void k_gemm(
    const unsigned short* __restrict__ X, const unsigned short* __restrict__ Wt,
    void* __restrict__ out, int M, int N, int K, int mode) {
  __shared__ alignas(16) unsigned short As[128 * 32];
  __shared__ alignas(16) unsigned short Bs[128 * 32];
  const int tid = threadIdx.x;
  const int lane = tid & 63, wave = tid >> 6;
  const int wr = wave >> 1, wc = wave & 1;
  const int lm = lane & 15, lq = lane >> 4;
  const int gx = gridDim.x;
  const int nwg = gx * gridDim.y;
  const int bid = blockIdx.y * gx + blockIdx.x;
  const int sz = (bid & 7) * (nwg >> 3) + (bid >> 3);
  const int m0 = (sz / gx) * 128, n0 = (sz % gx) * 128;
  const int srow = (lane >> 2);
  const int kcol = (lane & 3) * 8;
  f32x4 acc[4][4];
#pragma unroll
  for (int i = 0; i < 4; ++i)
#pragma unroll
    for (int j = 0; j < 4; ++j) acc[i][j] = (f32x4){0.f, 0.f, 0.f, 0.f};

  for (int k0 = 0; k0 < K; k0 += 32) {
#pragma unroll
    for (int p = 0; p < 2; ++p) {
      int row = wave * 32 + p * 16 + srow;
      g2l(X + (size_t)(m0 + row) * K + k0 + kcol, As + (wave * 2 + p) * 512);
      int n = n0 + row; if (n > N - 1) n = N - 1;
      g2l(Wt + (size_t)n * K + k0 + kcol, Bs + (wave * 2 + p) * 512);
    }
    __syncthreads();
    bf16x8 af[4], bfr[4];
#pragma unroll
    for (int i = 0; i < 4; ++i)
      af[i] = *(const bf16x8*)(As + (size_t)(wr * 64 + i * 16 + lm) * 32 + lq * 8);
#pragma unroll
    for (int j = 0; j < 4; ++j)
      bfr[j] = *(const bf16x8*)(Bs + (size_t)(wc * 64 + j * 16 + lm) * 32 + lq * 8);
#pragma unroll
    for (int i = 0; i < 4; ++i)
#pragma unroll
      for (int j = 0; j < 4; ++j)
        acc[i][j] = __builtin_amdgcn_mfma_f32_16x16x32_bf16(af[i], bfr[j], acc[i][j], 0, 0, 0);
    __syncthreads();
  }
#pragma unroll
  for (int i = 0; i < 4; ++i)
#pragma unroll
    for (int j = 0; j < 4; ++j) {
      int n = n0 + wc * 64 + j * 16 + lm;
      if (n >= N) continue;
      int mb = m0 + wr * 64 + i * 16 + lq * 4;
#pragma unroll
      for (int r = 0; r < 4; ++r) {
        float val = acc[i][j][r];
        size_t off = (size_t)(mb + r) * N + n;
        if (mode == 0) {
          ((float*)out)[off] = val;
        } else {
          if (mode == 2) val = tanhf(val);
          else if (mode == 3) val = 1.0f / (1.0f + __expf(-val));
          ((unsigned short*)out)[off] = f2bf(val);
        }
      }
    }
}

// ---------------- split (hi+lo) bf16 GEMM: hh + lh + hl (ll dropped, ~2^-17 rel) ----------------
__global__ __launch_bounds__(256) void k_gemm2(
    const unsigned short* __restrict__ Xh, const unsigned short* __restrict__ Xl, int xlo,
    const unsigned short* __restrict__ Wh, const unsigned short* __restrict__ Wl, int wlo,
    void* __restrict__ out, int M, int N, int K, int mode) {
  __shared__ alignas(16) unsigned short Ah[128 * 32];
  __shared__ alignas(16) unsigned short Al[128 * 32];
  __shared__ alignas(16) unsigned short Bh[128 * 32];
  __shared__ alignas(16) unsigned short Bl[128 * 32];
  const int tid = threadIdx.x;
  const int lane = tid & 63, wave = tid >> 6;
  const int wr = wave >> 1, wc = wave & 1;
  const int lm = lane & 15, lq = lane >> 4;
  const int gx = gridDim.x;
  const int nwg = gx * gridDim.y;
  const int bid = blockIdx.y * gx + blockIdx.x;
  const int sz = (bid & 7) * (nwg >> 3) + (bid >> 3);
  const int m0 = (sz / gx) * 128, n0 = (sz % gx) * 128;
  const int srow = (lane >> 2);
  const int kcol = (lane & 3) * 8;
  f32x4 acc[4][4];
#pragma unroll
  for (int i = 0; i < 4; ++i)
#pragma unroll
    for (int j = 0; j < 4; ++j) acc[i][j] = (f32x4){0.f, 0.f, 0.f, 0.f};

  for (int k0 = 0; k0 < K; k0 += 32) {
#pragma unroll
    for (int p = 0; p < 2; ++p) {
      int row = wave * 32 + p * 16 + srow;
      int off = (wave * 2 + p) * 512;
      size_t ga = (size_t)(m0 + row) * K + k0 + kcol;
      g2l(Xh + ga, Ah + off);
      if (xlo) g2l(Xl + ga, Al + off);
      int n = n0 + row; if (n > N - 1) n = N - 1;
      size_t gb = (size_t)n * K + k0 + kcol;
      g2l(Wh + gb, Bh + off);
      if (wlo) g2l(Wl + gb, Bl + off);
    }
    __syncthreads();
    bf16x8 ah[4], bh[4];
#pragma unroll
    for (int i = 0; i < 4; ++i)
      ah[i] = *(const bf16x8*)(Ah + (size_t)(wr * 64 + i * 16 + lm) * 32 + lq * 8);
#pragma unroll
    for (int j = 0; j < 4; ++j)
      bh[j] = *(const bf16x8*)(Bh + (size_t)(wc * 64 + j * 16 + lm) * 32 + lq * 8);
#pragma unroll
    for (int i = 0; i < 4; ++i)
#pragma unroll
      for (int j = 0; j < 4; ++j)
        acc[i][j] = __builtin_amdgcn_mfma_f32_16x16x32_bf16(ah[i], bh[j], acc[i][j], 0, 0, 0);
    if (xlo) {
      bf16x8 al[4];
#pragma unroll
      for (int i = 0; i < 4; ++i)
        al[i] = *(const bf16x8*)(Al + (size_t)(wr * 64 + i * 16 + lm) * 32 + lq * 8);
#pragma unroll
      for (int i = 0; i < 4; ++i)
#pragma unroll
        for (int j = 0; j < 4; ++j)
          acc[i][j] = __builtin_amdgcn_mfma_f32_16x16x32_bf16(al[i], bh[j], acc[i][j], 0, 0, 0);
    }
    if (wlo) {
      bf16x8 bl[4];
#pragma unroll
      for (int j = 0; j < 4; ++j)
        bl[j] = *(const bf16x8*)(Bl + (size_t)(wc * 64 + j * 16 + lm) * 32 + lq * 8);
#pragma unroll
      for (int i = 0; i < 4; ++i)
#pragma unroll
        for (int j = 0; j < 4; ++j)
          acc[i][j] = __builtin_amdgcn_mfma_f32_16x16x32_bf16(ah[i], bl[j], acc[i][j], 0, 0, 0);
    }
    __syncthreads();
  }
#pragma unroll
  for (int i = 0; i < 4; ++i)
#pragma unroll
    for (int j = 0; j < 4; ++j) {
      int n = n0 + wc * 64 + j * 16 + lm;
      if (n >= N) continue;
      int mb = m0 + wr * 64 + i * 16 + lq * 4;
#pragma unroll
      for (int r = 0; r < 4; ++r) {
        float val = acc[i][j][r];
        size_t off = (size_t)(mb + r) * N + n;
        if (mode == 0) {
          ((float*)out)[off] = val;
        } else {
          if (mode == 2) val = tanhf(val);
          else if (mode == 3) val = 1.0f / (1.0f + __expf(-val));
          ((unsigned short*)out)[off] = f2bf(val);
        }
      }
    }
}

// ---------------- pre-scan fused elementwise ----------------
__global__ __launch_bounds__(256) void k_pre(
    const float* __restrict__ rp, const float* __restrict__ kp, float* __restrict__ vp,
    const unsigned short* __restrict__ ww, const unsigned short* __restrict__ aa,
    const unsigned short* __restrict__ vv,
    const float* __restrict__ vfirst,
    const float* __restrict__ w0, const float* __restrict__ a0, const float* __restrict__ v0,
    const float* __restrict__ kkc, const float* __restrict__ kac,
    const float* __restrict__ rkw,
    unsigned short* __restrict__ rb, unsigned short* __restrict__ wb,
    unsigned short* __restrict__ kb, unsigned short* __restrict__ vb,
    unsigned short* __restrict__ ab, unsigned short* __restrict__ bb,
    float* __restrict__ dp) {
  int gw = blockIdx.x * 4 + (threadIdx.x >> 6);
  int l = threadIdx.x & 63;
  int h = gw & (H_ - 1);
  size_t bt = (size_t)(gw >> 5);
  size_t idx = bt * C_ + h * 64 + l;
  int c = h * 64 + l;
  float rf = rp[idx], kf = kp[idx], vr = vp[idx];
  float z = -(w0[c] + bf2f(ww[idx]));
  float sp = (z > 15.f) ? z : log1pf(__expf(z));
  float wv = -sp - 0.5f;
  float ag = 1.f / (1.f + __expf(-(a0[c] + bf2f(aa[idx]))));
  float sv = 1.f / (1.f + __expf(-(v0[c] + bf2f(vv[idx]))));
  float vf = vr + (vfirst[idx] - vr) * sv;
  float kkv = kf * kkc[c];
  float ss = kkv * kkv;
#pragma unroll
  for (int m = 1; m < 64; m <<= 1) ss += __shfl_xor(ss, m);
  float nrm = fmaxf(sqrtf(ss), 1e-12f);
  float kkn = kkv / nrm;
  float ks = kf * (1.f + (ag - 1.f) * kac[c]);
  vp[idx] = vf;
  float bon = rf * ks * rkw[c];
#pragma unroll
  for (int m = 1; m < 64; m <<= 1) bon += __shfl_xor(bon, m);
  if (l == 0) dp[bt * H_ + h] = bon;
  rb[idx] = f2bf(rf); wb[idx] = f2bf(wv); kb[idx] = f2bf(ks);
  vb[idx] = f2bf(vf); ab[idx] = f2bf(-kkn); bb[idx] = f2bf(kkn * ag);
}

// ================= chunk-parallel scan: ONE WAVE PER (HALF-)CHUNK =================
// Round-3 fused structure (zero barriers, zero LDS, in-wave readlane broadcast),
// with NC_=32 / L_=64: twice the waves -> 2 waves/SIMD of TLP to hide the
// readlane/FMA dependency stalls, with ZERO extra per-step work (round-4 lesson).
// P is stored to global in bf16 (history-coefficient path already bf16 via Zg).
__global__ __launch_bounds__(64) void k_scanP(
    const unsigned short* __restrict__ rb,
    const unsigned short* __restrict__ wb, const unsigned short* __restrict__ kb,
    const unsigned short* __restrict__ vb, const unsigned short* __restrict__ ab,
    const unsigned short* __restrict__ bb,
    unsigned short* __restrict__ Pg, float* __restrict__ Ug,
    unsigned short* __restrict__ Zg, float* __restrict__ o) {
  const int blk = blockIdx.x;
  const int c = blk & (NC_ - 1), bh = blk / NC_;
  const int b = bh >> 5, h = bh & (H_ - 1);
  const int l = threadIdx.x & 63;
  size_t base = (size_t)b * ((size_t)T_ * C_) + (size_t)(c * L_) * C_ + h * 64 + l;
  size_t zbase = (size_t)blk * (L_ * 64);
  float P[64], U[64];
#pragma unroll
  for (int k = 0; k < 64; ++k) { P[k] = (k == l) ? 1.f : 0.f; U[k] = 0.f; }
  float pr[4], pw[4], pk[4], pv[4], pb[4], pa[4];
#pragma unroll
  for (int s = 0; s < 4; ++s) {
    size_t a_ = base + (size_t)s * C_;
    pr[s] = bf2f(rb[a_]); pw[s] = bf2f(wb[a_]); pk[s] = bf2f(kb[a_]);
    pv[s] = bf2f(vb[a_]); pb[s] = bf2f(bb[a_]);
    pa[s] = bf2f(ab[base + (size_t)(s + 1) * C_]);  // a one step ahead
  }
  // t=0: sa over A=I, U=0  ->  saP = a_0[l] (lane-local), saU = 0
  float saP = bf2f(ab[base]), saU = 0.f;
  for (int t0 = 0; t0 < L_; t0 += 4) {
#pragma unroll
    for (int u = 0; u < 4; ++u) {
      const int t = t0 + u;
      float rl_ = pr[u], wl = pw[u], kl = pk[u], vl = pv[u], bl = pb[u], al = pa[u];
      if (t + 4 < L_) {
        size_t a_ = base + (size_t)(t + 4) * C_;
        pr[u] = bf2f(rb[a_]); pw[u] = bf2f(wb[a_]); pk[u] = bf2f(kb[a_]);
        pv[u] = bf2f(vb[a_]); pb[u] = bf2f(bb[a_]);
        int ta = t + 5; if (ta > L_ - 1) ta = L_ - 1;  // clamped value only feeds discarded sa_L
        pa[u] = bf2f(ab[base + (size_t)ta * C_]);
      }
      float ew = exp2f(wl * 1.4426950408889634f);
      float zz0 = 0.f, zz1 = 0.f, zz2 = 0.f, zz3 = 0.f;
      float yy0 = 0.f, yy1 = 0.f, yy2 = 0.f, yy3 = 0.f;
      float qp0 = 0.f, qp1 = 0.f, qp2 = 0.f, qp3 = 0.f;
      float qu0 = 0.f, qu1 = 0.f, qu2 = 0.f, qu3 = 0.f;
#pragma unroll
      for (int k = 0; k < 64; k += 4) {
#define STEPK(kk, ZZ, YY, QP, QU)                                        \
        {                                                                \
          float s_ew = rlane(ew, kk), s_b = rlane(bl, kk),               \
                s_k = rlane(kl, kk);                                     \
          float Pn = fmaf(P[kk], s_ew, s_b * saP);                       \
          float Un = fmaf(U[kk], s_ew, fmaf(s_b, saU, s_k * vl));        \
          P[kk] = Pn; U[kk] = Un;                                        \
          float s_r = rlane(rl_, kk), s_a = rlane(al, kk);               \
          ZZ = fmaf(s_r, Pn, ZZ); YY = fmaf(s_r, Un, YY);                \
          QP = fmaf(s_a, Pn, QP); QU = fmaf(s_a, Un, QU);                \
        }
        STEPK(k,     zz0, yy0, qp0, qu0)
        STEPK(k + 1, zz1, yy1, qp1, qu1)
        STEPK(k + 2, zz2, yy2, qp2, qu2)
        STEPK(k + 3, zz3, yy3, qp3, qu3)
#undef STEPK
      }
      o[base + (size_t)t * C_] = (yy0 + yy1) + (yy2 + yy3);
      Zg[zbase + t * 64 + l] = f2bf((zz0 + zz1) + (zz2 + zz3));
      saP = (qp0 + qp1) + (qp2 + qp3);
      saU = (qu0 + qu1) + (qu2 + qu3);
    }
  }
  size_t pb_ = (size_t)blk * 4096;
#pragma unroll
  for (int k4 = 0; k4 < 64; k4 += 4) {
    us4 pk4;
    pk4.x = f2bf(P[k4]); pk4.y = f2bf(P[k4 + 1]);
    pk4.z = f2bf(P[k4 + 2]); pk4.w = f2bf(P[k4 + 3]);
    *(us4*)(Pg + pb_ + (size_t)l * 64 + k4) = pk4;
  }
#pragma unroll
  for (int k = 0; k < 64; ++k) Ug[pb_ + (size_t)k * 64 + l] = U[k];
}

// ---------------- chunk combine: column-parallel (4 blocks per bh) ----------------
// S' = A S + U per chunk, serial in c; columns of S are independent, so each of
// 4 blocks owns a 16-column slice -> 256 blocks = full GPU. P (bf16) staged to
// LDS per chunk; all LDS reads are broadcast-pattern (conflict-free).
__global__ __launch_bounds__(256) void k_scanC(
    const unsigned short* __restrict__ Pg, const float* __restrict__ Ug,
    const float* __restrict__ s0, float* __restrict__ Scg, float* __restrict__ sout) {
  const int bh = blockIdx.x >> 2, q = blockIdx.x & 3;
  const int tid = threadIdx.x;
  const int col = tid & 15;
  const int r0 = (tid >> 4) * 4;
  const int colg = q * 16 + col;
  __shared__ float Sb[64][16];
  __shared__ alignas(16) unsigned short Pb[4096];
  float sreg[4];
#pragma unroll
  for (int rr = 0; rr < 4; ++rr) {
    float v = s0[(size_t)bh * 4096 + (r0 + rr) * 64 + colg];
    sreg[rr] = v; Sb[r0 + rr][col] = v;
  }
  {
    size_t cb0 = ((size_t)bh * NC_) * 4096;
    *(us4*)(Pb + tid * 16)      = *(const us4*)(Pg + cb0 + tid * 16);
    *(us4*)(Pb + tid * 16 + 4)  = *(const us4*)(Pg + cb0 + tid * 16 + 4);
    *(us4*)(Pb + tid * 16 + 8)  = *(const us4*)(Pg + cb0 + tid * 16 + 8);
    *(us4*)(Pb + tid * 16 + 12) = *(const us4*)(Pg + cb0 + tid * 16 + 12);
  }
  __syncthreads();
  for (int c = 0; c < NC_; ++c) {
    size_t cb = ((size_t)bh * NC_ + c) * 4096;
#pragma unroll
    for (int rr = 0; rr < 4; ++rr)
      Scg[cb + (size_t)(r0 + rr) * 64 + colg] = sreg[rr];
    float acc0 = Ug[cb + (size_t)r0 * 64 + colg];
    float acc1 = Ug[cb + (size_t)(r0 + 1) * 64 + colg];
    float acc2 = Ug[cb + (size_t)(r0 + 2) * 64 + colg];
    float acc3 = Ug[cb + (size_t)(r0 + 3) * 64 + colg];
    for (int j = 0; j < 64; ++j) {
      float s = Sb[j][col];
      us4 p4 = *(const us4*)(Pb + j * 64 + r0);
      acc0 = fmaf(bf2f(p4.x), s, acc0);
      acc1 = fmaf(bf2f(p4.y), s, acc1);
      acc2 = fmaf(bf2f(p4.z), s, acc2);
      acc3 = fmaf(bf2f(p4.w), s, acc3);
    }
    __syncthreads();
    Sb[r0][col] = acc0; Sb[r0 + 1][col] = acc1;
    Sb[r0 + 2][col] = acc2; Sb[r0 + 3][col] = acc3;
    sreg[0] = acc0; sreg[1] = acc1; sreg[2] = acc2; sreg[3] = acc3;
    if (c + 1 < NC_) {
      size_t cbn = cb + 4096;
      *(us4*)(Pb + tid * 16)      = *(const us4*)(Pg + cbn + tid * 16);
      *(us4*)(Pb + tid * 16 + 4)  = *(const us4*)(Pg + cbn + tid * 16 + 4);
      *(us4*)(Pb + tid * 16 + 8)  = *(const us4*)(Pg + cbn + tid * 16 + 8);
      *(us4*)(Pb + tid * 16 + 12) = *(const us4*)(Pg + cbn + tid * 16 + 12);
    }
    __syncthreads();
  }
#pragma unroll
  for (int rr = 0; rr < 4; ++rr)
    sout[(size_t)bh * 4096 + (r0 + rr) * 64 + colg] = sreg[rr];
}

// ---------------- apply chunk-start state: o += Z @ S0 (per chunk) ----------------
__global__ __launch_bounds__(256) void k_scanO(
    const unsigned short* __restrict__ Zg, const float* __restrict__ Scg,
    float* __restrict__ o) {
  const int blk = blockIdx.x;
  const int c = blk & (NC_ - 1), bh = blk / NC_;
  const int b = bh >> 5, h = bh & (H_ - 1);
  const int l = threadIdx.x & 63;
  const int w = threadIdx.x >> 6;
  float S[64];
  const float* Sp = Scg + (size_t)blk * 4096 + l;
#pragma unroll
  for (int k = 0; k < 64; ++k) S[k] = Sp[(size_t)k * 64];
  size_t zb = (size_t)blk * (L_ * 64);
  size_t ob = (size_t)b * ((size_t)T_ * C_) + (size_t)(c * L_) * C_ + h * 64 + l;
  for (int tt = 0; tt < L_ / 4; ++tt) {
    int t = w * (L_ / 4) + tt;
    float zv = bf2f(Zg[zb + t * 64 + l]);  // lane l holds z_t[l]
    float a0_ = 0.f, a1_ = 0.f, a2_ = 0.f, a3_ = 0.f;
#pragma unroll
    for (int k = 0; k < 64; k += 4) {
      a0_ = fmaf(rlane(zv, k), S[k], a0_);
      a1_ = fmaf(rlane(zv, k + 1), S[k + 1], a1_);
      a2_ = fmaf(rlane(zv, k + 2), S[k + 2], a2_);
      a3_ = fmaf(rlane(zv, k + 3), S[k + 3], a3_);
    }
    o[ob + (size_t)t * C_] += (a0_ + a1_) + (a2_ + a3_);
  }
}

// ---------------- post-scan: GroupNorm + bonus + *g (bf16) -> bf16 ----------------
__global__ __launch_bounds__(256) void k_post(
    const float* __restrict__ o, const float* __restrict__ vp,
    const unsigned short* __restrict__ gp,
    const float* __restrict__ dp,
    const float* __restrict__ lnw, const float* __restrict__ lnb,
    unsigned short* __restrict__ z) {
  int gw = blockIdx.x * 4 + (threadIdx.x >> 6);
  int l = threadIdx.x & 63;
  int h = gw & (H_ - 1);
  size_t bt = (size_t)(gw >> 5);
  size_t idx = bt * C_ + h * 64 + l;
  int c = h * 64 + l;
  float ov = o[idx];
  float s1 = ov;
#pragma unroll
  for (int m = 1; m < 64; m <<= 1) s1 += __shfl_xor(s1, m);
  float mu = s1 * (1.f / 64.f);
  float d = ov - mu;
  float s2 = d * d;
#pragma unroll
  for (int m = 1; m < 64; m <<= 1) s2 += __shfl_xor(s2, m);
  float var = s2 * (1.f / 64.f);
  float y = d * rsqrtf(var + 6.4e-4f);
  y = y * lnw[c] + lnb[c];
  y = fmaf(dp[bt * H_ + h], vp[idx], y);
  z[idx] = f2bf(y * bf2f(gp[idx]));
}

extern "C" void kernel_launch(void* const* d_in, const int* in_sizes, int n_in,
                              void* d_out, int out_size, void* d_ws, size_t ws_size,
                              hipStream_t stream) {
  const float* x      = (const float*)d_in[0];
  const float* shift  = (const float*)d_in[1];
  const float* wkv    = (const float*)d_in[2];
  const float* vfirst = (const float*)d_in[3];
  const float* x_r    = (const float*)d_in[4];
  const float* x_w    = (const float*)d_in[5];
  const float* x_k    = (const float*)d_in[6];
  const float* x_v    = (const float*)d_in[7];
  const float* x_a    = (const float*)d_in[8];
  const float* x_g    = (const float*)d_in[9];
  const float* w0     = (const float*)d_in[10];
  const float* w1     = (const float*)d_in[11];
  const float* w2     = (const float*)d_in[12];
  const float* a0     = (const float*)d_in[13];
  const float* a1     = (const float*)d_in[14];
  const float* a2     = (const float*)d_in[15];
  const float* v0     = (const float*)d_in[16];
  const float* v1     = (const float*)d_in[17];
  const float* v2     = (const float*)d_in[18];
  const float* g1     = (const float*)d_in[19];
  const float* g2     = (const float*)d_in[20];
  const float* k_k    = (const float*)d_in[21];
  const float* k_a    = (const float*)d_in[22];
  const float* r_k    = (const float*)d_in[23];
  const float* W_r    = (const float*)d_in[24];
  const float* W_k    = (const float*)d_in[25];
  const float* W_v    = (const float*)d_in[26];
  const float* W_o    = (const float*)d_in[27];
  const float* ln_w   = (const float*)d_in[28];
  const float* ln_b   = (const float*)d_in[29];

  // ---- workspace plan: ~213 MiB (footprint identical to passing version) ----
  char* wp = (char*)d_ws;
  auto alloc = [&](size_t bytes) { char* p = wp; wp += (bytes + 255) & ~(size_t)255; return p; };
  const size_t SB = BTC_ * 2;
  const size_t SF = BTC_ * 4;

  unsigned short* w1t = (unsigned short*)alloc((size_t)C_ * 64 * 2);
  unsigned short* w2t = (unsigned short*)alloc((size_t)C_ * 64 * 2);
  unsigned short* a1t = (unsigned short*)alloc((size_t)C_ * 64 * 2);
  unsigned short* a2t = (unsigned short*)alloc((size_t)C_ * 64 * 2);
  unsigned short* v1t = (unsigned short*)alloc((size_t)C_ * 32 * 2);
  unsigned short* v2t = (unsigned short*)alloc((size_t)C_ * 32 * 2);
  unsigned short* g1t = (unsigned short*)alloc((size_t)C_ * 128 * 2);
  unsigned short* g2t = (unsigned short*)alloc((size_t)C_ * 128 * 2);
  unsigned short* hw  = (unsigned short*)alloc((size_t)BT_ * 64 * 2);
  unsigned short* ha  = (unsigned short*)alloc((size_t)BT_ * 64 * 2);
  unsigned short* hv  = (unsigned short*)alloc((size_t)BT_ * 32 * 2);
  unsigned short* hg  = (unsigned short*)alloc((size_t)BT_ * 128 * 2);
  unsigned short* Wt2 = (unsigned short*)alloc((size_t)C_ * C_ * 2 * 2); // hi|lo; later Zg (bf16)
  float* dp           = (float*)alloc((size_t)BT_ * H_ * 4);
  unsigned short* xw  = (unsigned short*)alloc(SB);      // mix-w -> wb -> Scg lo half (f32)
  unsigned short* xa  = (unsigned short*)alloc(SB);      // mix-a -> ab -> Scg hi half
  unsigned short* xg  = (unsigned short*)alloc(SB);
  unsigned short* xr2 = (unsigned short*)alloc(2 * SB); // -> kbuf f32 -> Ug (f32) -> zbuf
  unsigned short* xk2 = (unsigned short*)alloc(2 * SB); // -> vbuf f32
  unsigned short* xv2 = (unsigned short*)alloc(2 * SB); // -> scan rb|kb
  float* rbuf         = (float*)alloc(SF);              // r f32 -> g bf16 | Pg bf16
  unsigned short* vbb = (unsigned short*)alloc(SB);

  unsigned short* Wh = Wt2;
  unsigned short* Wl = Wt2 + (size_t)C_ * C_;
  unsigned short* xr_h = xr2, *xr_l = xr2 + BTC_;
  unsigned short* xk_h = xk2, *xk_l = xk2 + BTC_;
  unsigned short* xv_h = xv2, *xv_l = xv2 + BTC_;
  float* kbuf = (float*)xr2;
  float* vbuf = (float*)xk2;
  unsigned short* rb = xv2;
  unsigned short* kb = xv2 + BTC_;
  unsigned short* gb16 = (unsigned short*)rbuf;            // g bf16 (first half of rbuf)
  unsigned short* Pgb  = (unsigned short*)rbuf + BTC_;     // P bf16 (second half of rbuf)
  float* Ugf = (float*)xr2;                                // U f32 (fills xr2 at NC_=32)
  unsigned short* zbuf = (unsigned short*)xr2;             // k_post out (Ug dead by then)
  unsigned short* zg = Wt2;                                // z bf16 (Wt2 dead here)
  float* Scg = (float*)xw;                                 // chunk-start states, spans xw+xa

  float* outp  = (float*)d_out;
  float* xlast = outp + BTC_;
  float* soutp = outp + BTC_ + (size_t)B_ * C_;
  float* obuf  = outp;

  auto tr = [&](const float* in, unsigned short* out, int R, int Cc) {
    k_tr<<<dim3(Cc / 32, R / 32), 256, 0, stream>>>(in, out, R, Cc);
  };
  auto gemm = [&](const unsigned short* X, const unsigned short* Wtp, void* out,
                  int M, int N, int K, int mode) {
    k_gemm<<<dim3((N + 127) / 128, M / 128), 256, 0, stream>>>(X, Wtp, out, M, N, K, mode);
  };
  auto gemm2 = [&](const unsigned short* Xh_, const unsigned short* Xl_, int xlo,
                   const unsigned short* Wh_, const unsigned short* Wl_, int wlo,
                   void* out, int M, int N, int K, int mode) {
    k_gemm2<<<dim3((N + 127) / 128, M / 128), 256, 0, stream>>>(Xh_, Xl_, xlo, Wh_, Wl_, wlo,
                                                                out, M, N, K, mode);
  };

  k_mix<<<(int)(BTC_ / 4 / 256), 256, 0, stream>>>(x, shift, x_r, x_w, x_k, x_v, x_a, x_g,
                                                   xr_h, xr_l, xk_h, xk_l, xv_h, xv_l,
                                                   xw, xa, xg, xlast);
  tr(w1, w1t, C_, 64);  tr(w2, w2t, 64, C_);
  tr(a1, a1t, C_, 64);  tr(a2, a2t, 64, C_);
  tr(v1, v1t, C_, 32);  tr(v2, v2t, 32, C_);
  tr(g1, g1t, C_, 128); tr(g2, g2t, 128, C_);

  // LoRA stage 1
  gemm(xw, w1t, hw, BT_, 64, C_, 2);
  gemm(xa, a1t, ha, BT_, 64, C_, 1);
  gemm2(xv_h, xv_l, 1, v1t, nullptr, 0, hv, BT_, 32, C_, 1);
  gemm(xg, g1t, hg, BT_, 128, C_, 3);

  // big projections, split precision (hh + lh + hl)
  k_trs<<<dim3(C_ / 32, C_ / 32), 256, 0, stream>>>(W_r, Wh, Wl, C_, C_);
  gemm2(xr_h, xr_l, 1, Wh, Wl, 1, rbuf, BT_, C_, C_, 0);
  k_trs<<<dim3(C_ / 32, C_ / 32), 256, 0, stream>>>(W_k, Wh, Wl, C_, C_);
  gemm2(xk_h, xk_l, 1, Wh, Wl, 1, kbuf, BT_, C_, C_, 0);
  k_trs<<<dim3(C_ / 32, C_ / 32), 256, 0, stream>>>(W_v, Wh, Wl, C_, C_);
  gemm2(xv_h, xv_l, 1, Wh, Wl, 1, vbuf, BT_, C_, C_, 0);

  // LoRA stage 2 into dead mix buffers
  gemm(hw, w2t, xw, BT_, C_, 64, 1);
  gemm(ha, a2t, xa, BT_, C_, 64, 1);
  gemm(hv, v2t, xg, BT_, C_, 32, 1);

  k_pre<<<BT_ * H_ / 4, 256, 0, stream>>>(rbuf, kbuf, vbuf, xw, xa, xg, vfirst,
                                          w0, a0, v0, k_k, k_a, r_k,
                                          rb, xw, kb, vbb, xa, xg, dp);

  // g in bf16 (r dead; first half of rbuf)
  gemm(hg, g2t, gb16, BT_, C_, 128, 1);

  // chunk-parallel scan: P/U/z/y in one pass, column-parallel combine, apply S0
  k_scanP<<<B_ * H_ * NC_, 64, 0, stream>>>(rb, xw, kb, vbb, xa, xg, Pgb, Ugf, zg, obuf);
  k_scanC<<<B_ * H_ * 4, 256, 0, stream>>>(Pgb, Ugf, wkv, Scg, soutp);
  k_scanO<<<B_ * H_ * NC_, 256, 0, stream>>>(zg, Scg, obuf);

  k_post<<<BT_ * H_ / 4, 256, 0, stream>>>(obuf, vbuf, gb16, dp, ln_w, ln_b, zbuf);

  tr(W_o, Wh, C_, C_);
  gemm(zbuf, Wh, outp, BT_, C_, C_, 0);
}

// Round 7
// 1313.145 us; speedup vs baseline: 1.2107x; 1.0503x over previous
//
#include <hip/hip_runtime.h>
#include <cstdint>
#include <cmath>

#define B_ 2
#define T_ 2048
#define C_ 2048
#define H_ 32
#define BT_ (B_ * T_)
#define BTC_ ((size_t)B_ * T_ * C_)
#define L_ 64
#define NC_ 32

typedef __attribute__((ext_vector_type(4))) float f32x4;
typedef __attribute__((ext_vector_type(2))) float f32x2;
typedef __attribute__((ext_vector_type(8))) short bf16x8;
typedef __attribute__((ext_vector_type(4))) unsigned short us4;
typedef __attribute__((ext_vector_type(4))) int i32x4;

__device__ __forceinline__ unsigned short f2bf(float f) {
  union { float f; unsigned int u; } c; c.f = f;
  unsigned int u = c.u;
  return (unsigned short)((u + 0x7FFFu + ((u >> 16) & 1u)) >> 16);
}
__device__ __forceinline__ float bf2f(unsigned short h) {
  union { unsigned int u; float f; } c; c.u = ((unsigned int)h) << 16;
  return c.f;
}
__device__ __forceinline__ float uaf(unsigned int u) {
  union { unsigned int u; float f; } c; c.u = u; return c.f;
}
__device__ __forceinline__ float rlane(float v, int lane) {
  return __int_as_float(__builtin_amdgcn_readlane(__float_as_int(v), lane));
}
__device__ __forceinline__ void split4(f32x4 v, us4& h, us4& l) {
  h.x = f2bf(v.x); l.x = f2bf(v.x - bf2f(h.x));
  h.y = f2bf(v.y); l.y = f2bf(v.y - bf2f(h.y));
  h.z = f2bf(v.z); l.z = f2bf(v.z - bf2f(h.z));
  h.w = f2bf(v.w); l.w = f2bf(v.w - bf2f(h.w));
}
// async global->LDS, 16 B per lane; LDS dest = wave-uniform base + lane*16
__device__ __forceinline__ void g2l(const void* g, void* l) {
  __builtin_amdgcn_global_load_lds((const __attribute__((address_space(1))) void*)g,
                                   (__attribute__((address_space(3))) void*)l, 16, 0, 0);
}

// ---------------- token shift + mixes: r/k/v as bf16 hi+lo pairs, w/a/g bf16 ----------------
__global__ __launch_bounds__(256) void k_mix(
    const float* __restrict__ x, const float* __restrict__ shift,
    const float* __restrict__ m_r, const float* __restrict__ m_w,
    const float* __restrict__ m_k, const float* __restrict__ m_v,
    const float* __restrict__ m_a, const float* __restrict__ m_g,
    unsigned short* __restrict__ r_h, unsigned short* __restrict__ r_l,
    unsigned short* __restrict__ k_h, unsigned short* __restrict__ k_l,
    unsigned short* __restrict__ v_h, unsigned short* __restrict__ v_l,
    unsigned short* __restrict__ o_w, unsigned short* __restrict__ o_a,
    unsigned short* __restrict__ o_g,
    float* __restrict__ xlast) {
  size_t i4 = ((size_t)blockIdx.x * 256 + threadIdx.x) * 4;
  int c = (int)(i4 % C_);
  size_t bt = i4 / C_;
  int t = (int)(bt % T_);
  int b = (int)(bt / T_);
  f32x4 xv = *(const f32x4*)(x + i4);
  f32x4 pv = (t == 0) ? *(const f32x4*)(shift + (size_t)b * C_ + c)
                      : *(const f32x4*)(x + i4 - C_);
  f32x4 dx = pv - xv;
#define MIXHL(mp, oh, ol) { f32x4 mm = *(const f32x4*)(mp + c); f32x4 rr = xv + dx * mm; \
    us4 hh, ll; split4(rr, hh, ll); *(us4*)(oh + i4) = hh; *(us4*)(ol + i4) = ll; }
#define MIXH(mp, oh) { f32x4 mm = *(const f32x4*)(mp + c); f32x4 rr = xv + dx * mm; \
    us4 pk; pk.x = f2bf(rr.x); pk.y = f2bf(rr.y); pk.z = f2bf(rr.z); pk.w = f2bf(rr.w); \
    *(us4*)(oh + i4) = pk; }
  MIXHL(m_r, r_h, r_l) MIXHL(m_k, k_h, k_l) MIXHL(m_v, v_h, v_l)
  MIXH(m_w, o_w) MIXH(m_a, o_a) MIXH(m_g, o_g)
#undef MIXHL
#undef MIXH
  if (t == T_ - 1) *(f32x4*)(xlast + (size_t)b * C_ + c) = xv;
}

// ---------------- f32 [R][Cc] -> bf16 [Cc][R] transpose ----------------
__global__ __launch_bounds__(256) void k_tr(const float* __restrict__ in,
                                            unsigned short* __restrict__ out,
                                            int R, int Cc) {
  __shared__ float tile[32][33];
  int c0 = blockIdx.x * 32, r0 = blockIdx.y * 32;
  int tid = threadIdx.x;
  int rr = tid >> 3, c4 = (tid & 7) * 4;
  f32x4 v = *(const f32x4*)(in + (size_t)(r0 + rr) * Cc + c0 + c4);
  tile[rr][c4] = v.x; tile[rr][c4 + 1] = v.y; tile[rr][c4 + 2] = v.z; tile[rr][c4 + 3] = v.w;
  __syncthreads();
  int cc = tid >> 3, r4 = (tid & 7) * 4;
  us4 o;
  o.x = f2bf(tile[r4][cc]); o.y = f2bf(tile[r4 + 1][cc]);
  o.z = f2bf(tile[r4 + 2][cc]); o.w = f2bf(tile[r4 + 3][cc]);
  *(us4*)(out + (size_t)(c0 + cc) * R + r0 + r4) = o;
}

// ---------------- f32 [R][Cc] -> bf16 hi+lo [Cc][R] split transpose ----------------
__global__ __launch_bounds__(256) void k_trs(const float* __restrict__ in,
                                             unsigned short* __restrict__ oh,
                                             unsigned short* __restrict__ ol,
                                             int R, int Cc) {
  __shared__ float tile[32][33];
  int c0 = blockIdx.x * 32, r0 = blockIdx.y * 32;
  int tid = threadIdx.x;
  int rr = tid >> 3, c4 = (tid & 7) * 4;
  f32x4 v = *(const f32x4*)(in + (size_t)(r0 + rr) * Cc + c0 + c4);
  tile[rr][c4] = v.x; tile[rr][c4 + 1] = v.y; tile[rr][c4 + 2] = v.z; tile[rr][c4 + 3] = v.w;
  __syncthreads();
  int cc = tid >> 3, r4 = (tid & 7) * 4;
  f32x4 w = { tile[r4][cc], tile[r4 + 1][cc], tile[r4 + 2][cc], tile[r4 + 3][cc] };
  us4 h, l; split4(w, h, l);
  size_t o = (size_t)(c0 + cc) * R + r0 + r4;
  *(us4*)(oh + o) = h; *(us4*)(ol + o) = l;
}

// ---------------- bf16 GEMM: C[M,N] = X[M,K] @ Wt[N,K]^T (global_load_lds staging) ----------------
// XCD-aware bijective block swizzle (T1): all launch grids have nwg % 8 == 0.
__global__ __launch_bounds__(256) void k_gemm(
    const unsigned short* __restrict__ X, const unsigned short* __restrict__ Wt,
    void* __restrict__ out, int M, int N, int K, int mode) {
  __shared__ alignas(16) unsigned short As[128 * 32];
  __shared__ alignas(16) unsigned short Bs[128 * 32];
  const int tid = threadIdx.x;
  const int lane = tid & 63, wave = tid >> 6;
  const int wr = wave >> 1, wc = wave & 1;
  const int lm = lane & 15, lq = lane >> 4;
  const int gx = gridDim.x;
  const int nwg = gx * gridDim.y;
  const int bid = blockIdx.y * gx + blockIdx.x;
  const int sz = (bid & 7) * (nwg >> 3) + (bid >> 3);
  const int m0 = (sz / gx) * 128, n0 = (sz % gx) * 128;
  const int srow = (lane >> 2);
  const int kcol = (lane & 3) * 8;
  f32x4 acc[4][4];
#pragma unroll
  for (int i = 0; i < 4; ++i)
#pragma unroll
    for (int j = 0; j < 4; ++j) acc[i][j] = (f32x4){0.f, 0.f, 0.f, 0.f};

  for (int k0 = 0; k0 < K; k0 += 32) {
#pragma unroll
    for (int p = 0; p < 2; ++p) {
      int row = wave * 32 + p * 16 + srow;
      g2l(X + (size_t)(m0 + row) * K + k0 + kcol, As + (wave * 2 + p) * 512);
      int n = n0 + row; if (n > N - 1) n = N - 1;
      g2l(Wt + (size_t)n * K + k0 + kcol, Bs + (wave * 2 + p) * 512);
    }
    __syncthreads();
    bf16x8 af[4], bfr[4];
#pragma unroll
    for (int i = 0; i < 4; ++i)
      af[i] = *(const bf16x8*)(As + (size_t)(wr * 64 + i * 16 + lm) * 32 + lq * 8);
#pragma unroll
    for (int j = 0; j < 4; ++j)
      bfr[j] = *(const bf16x8*)(Bs + (size_t)(wc * 64 + j * 16 + lm) * 32 + lq * 8);
#pragma unroll
    for (int i = 0; i < 4; ++i)
#pragma unroll
      for (int j = 0; j < 4; ++j)
        acc[i][j] = __builtin_amdgcn_mfma_f32_16x16x32_bf16(af[i], bfr[j], acc[i][j], 0, 0, 0);
    __syncthreads();
  }
#pragma unroll
  for (int i = 0; i < 4; ++i)
#pragma unroll
    for (int j = 0; j < 4; ++j) {
      int n = n0 + wc * 64 + j * 16 + lm;
      if (n >= N) continue;
      int mb = m0 + wr * 64 + i * 16 + lq * 4;
#pragma unroll
      for (int r = 0; r < 4; ++r) {
        float val = acc[i][j][r];
        size_t off = (size_t)(mb + r) * N + n;
        if (mode == 0) {
          ((float*)out)[off] = val;
        } else {
          if (mode == 2) val = tanhf(val);
          else if (mode == 3) val = 1.0f / (1.0f + __expf(-val));
          ((unsigned short*)out)[off] = f2bf(val);
        }
      }
    }
}

// ---------------- split (hi+lo) bf16 GEMM: hh + lh + hl (ll dropped, ~2^-17 rel) ----------------
__global__ __launch_bounds__(256) void k_gemm2(
    const unsigned short* __restrict__ Xh, const unsigned short* __restrict__ Xl, int xlo,
    const unsigned short* __restrict__ Wh, const unsigned short* __restrict__ Wl, int wlo,
    void* __restrict__ out, int M, int N, int K, int mode) {
  __shared__ alignas(16) unsigned short Ah[128 * 32];
  __shared__ alignas(16) unsigned short Al[128 * 32];
  __shared__ alignas(16) unsigned short Bh[128 * 32];
  __shared__ alignas(16) unsigned short Bl[128 * 32];
  const int tid = threadIdx.x;
  const int lane = tid & 63, wave = tid >> 6;
  const int wr = wave >> 1, wc = wave & 1;
  const int lm = lane & 15, lq = lane >> 4;
  const int gx = gridDim.x;
  const int nwg = gx * gridDim.y;
  const int bid = blockIdx.y * gx + blockIdx.x;
  const int sz = (bid & 7) * (nwg >> 3) + (bid >> 3);
  const int m0 = (sz / gx) * 128, n0 = (sz % gx) * 128;
  const int srow = (lane >> 2);
  const int kcol = (lane & 3) * 8;
  f32x4 acc[4][4];
#pragma unroll
  for (int i = 0; i < 4; ++i)
#pragma unroll
    for (int j = 0; j < 4; ++j) acc[i][j] = (f32x4){0.f, 0.f, 0.f, 0.f};

  for (int k0 = 0; k0 < K; k0 += 32) {
#pragma unroll
    for (int p = 0; p < 2; ++p) {
      int row = wave * 32 + p * 16 + srow;
      int off = (wave * 2 + p) * 512;
      size_t ga = (size_t)(m0 + row) * K + k0 + kcol;
      g2l(Xh + ga, Ah + off);
      if (xlo) g2l(Xl + ga, Al + off);
      int n = n0 + row; if (n > N - 1) n = N - 1;
      size_t gb = (size_t)n * K + k0 + kcol;
      g2l(Wh + gb, Bh + off);
      if (wlo) g2l(Wl + gb, Bl + off);
    }
    __syncthreads();
    bf16x8 ah[4], bh[4];
#pragma unroll
    for (int i = 0; i < 4; ++i)
      ah[i] = *(const bf16x8*)(Ah + (size_t)(wr * 64 + i * 16 + lm) * 32 + lq * 8);
#pragma unroll
    for (int j = 0; j < 4; ++j)
      bh[j] = *(const bf16x8*)(Bh + (size_t)(wc * 64 + j * 16 + lm) * 32 + lq * 8);
#pragma unroll
    for (int i = 0; i < 4; ++i)
#pragma unroll
      for (int j = 0; j < 4; ++j)
        acc[i][j] = __builtin_amdgcn_mfma_f32_16x16x32_bf16(ah[i], bh[j], acc[i][j], 0, 0, 0);
    if (xlo) {
      bf16x8 al[4];
#pragma unroll
      for (int i = 0; i < 4; ++i)
        al[i] = *(const bf16x8*)(Al + (size_t)(wr * 64 + i * 16 + lm) * 32 + lq * 8);
#pragma unroll
      for (int i = 0; i < 4; ++i)
#pragma unroll
        for (int j = 0; j < 4; ++j)
          acc[i][j] = __builtin_amdgcn_mfma_f32_16x16x32_bf16(al[i], bh[j], acc[i][j], 0, 0, 0);
    }
    if (wlo) {
      bf16x8 bl[4];
#pragma unroll
      for (int j = 0; j < 4; ++j)
        bl[j] = *(const bf16x8*)(Bl + (size_t)(wc * 64 + j * 16 + lm) * 32 + lq * 8);
#pragma unroll
      for (int i = 0; i < 4; ++i)
#pragma unroll
        for (int j = 0; j < 4; ++j)
          acc[i][j] = __builtin_amdgcn_mfma_f32_16x16x32_bf16(ah[i], bl[j], acc[i][j], 0, 0, 0);
    }
    __syncthreads();
  }
#pragma unroll
  for (int i = 0; i < 4; ++i)
#pragma unroll
    for (int j = 0; j < 4; ++j) {
      int n = n0 + wc * 64 + j * 16 + lm;
      if (n >= N) continue;
      int mb = m0 + wr * 64 + i * 16 + lq * 4;
#pragma unroll
      for (int r = 0; r < 4; ++r) {
        float val = acc[i][j][r];
        size_t off = (size_t)(mb + r) * N + n;
        if (mode == 0) {
          ((float*)out)[off] = val;
        } else {
          if (mode == 2) val = tanhf(val);
          else if (mode == 3) val = 1.0f / (1.0f + __expf(-val));
          ((unsigned short*)out)[off] = f2bf(val);
        }
      }
    }
}

// ---------------- pre-scan fused elementwise ----------------
// Outputs for the scan: wb (bf16), ab (bf16), rb (bf16), vb (bf16),
// bk (u32 = k_bf16<<16 | b_bf16) -- packed so one readlane broadcasts both.
__global__ __launch_bounds__(256) void k_pre(
    const float* __restrict__ rp, const float* __restrict__ kp, float* __restrict__ vp,
    const unsigned short* __restrict__ ww, const unsigned short* __restrict__ aa,
    const unsigned short* __restrict__ vv,
    const float* __restrict__ vfirst,
    const float* __restrict__ w0, const float* __restrict__ a0, const float* __restrict__ v0,
    const float* __restrict__ kkc, const float* __restrict__ kac,
    const float* __restrict__ rkw,
    unsigned short* __restrict__ wb, unsigned short* __restrict__ ab,
    unsigned short* __restrict__ rb, unsigned short* __restrict__ vb,
    unsigned int* __restrict__ bk,
    float* __restrict__ dp) {
  int gw = blockIdx.x * 4 + (threadIdx.x >> 6);
  int l = threadIdx.x & 63;
  int h = gw & (H_ - 1);
  size_t bt = (size_t)(gw >> 5);
  size_t idx = bt * C_ + h * 64 + l;
  int c = h * 64 + l;
  float rf = rp[idx], kf = kp[idx], vr = vp[idx];
  float z = -(w0[c] + bf2f(ww[idx]));
  float sp = (z > 15.f) ? z : log1pf(__expf(z));
  float wv = -sp - 0.5f;
  float ag = 1.f / (1.f + __expf(-(a0[c] + bf2f(aa[idx]))));
  float sv = 1.f / (1.f + __expf(-(v0[c] + bf2f(vv[idx]))));
  float vf = vr + (vfirst[idx] - vr) * sv;
  float kkv = kf * kkc[c];
  float ss = kkv * kkv;
#pragma unroll
  for (int m = 1; m < 64; m <<= 1) ss += __shfl_xor(ss, m);
  float nrm = fmaxf(sqrtf(ss), 1e-12f);
  float kkn = kkv / nrm;
  float ks = kf * (1.f + (ag - 1.f) * kac[c]);
  vp[idx] = vf;
  float bon = rf * ks * rkw[c];
#pragma unroll
  for (int m = 1; m < 64; m <<= 1) bon += __shfl_xor(bon, m);
  if (l == 0) dp[bt * H_ + h] = bon;
  wb[idx] = f2bf(wv);
  ab[idx] = f2bf(-kkn);
  rb[idx] = f2bf(rf);
  vb[idx] = f2bf(vf);
  bk[idx] = ((unsigned int)f2bf(ks) << 16) | (unsigned int)f2bf(kkn * ag);
}

// ================= chunk-parallel scan: ONE WAVE PER (HALF-)CHUNK =================
// Fused zero-barrier structure. This round: t-loop ROLLED (unroll 1, I-cache fit,
// ~7KB body vs ~30KB) with distance-2 named-register prefetch, and k|b broadcast
// from a single packed u32 readlane (unpack = uniform shift/and -> SALU).
// Arithmetic bit-identical to round 6 (same values, same FMA order).
__global__ __launch_bounds__(64) void k_scanP(
    const unsigned short* __restrict__ wb, const unsigned short* __restrict__ ab,
    const unsigned short* __restrict__ rb, const unsigned short* __restrict__ vb,
    const unsigned int* __restrict__ bk,
    unsigned short* __restrict__ Pg, float* __restrict__ Ug,
    unsigned short* __restrict__ Zg, float* __restrict__ o) {
  const int blk = blockIdx.x;
  const int c = blk & (NC_ - 1), bh = blk / NC_;
  const int b = bh >> 5, h = bh & (H_ - 1);
  const int l = threadIdx.x & 63;
  size_t base = (size_t)b * ((size_t)T_ * C_) + (size_t)(c * L_) * C_ + h * 64 + l;
  size_t zbase = (size_t)blk * (L_ * 64);
  float P[64], U[64];
#pragma unroll
  for (int k = 0; k < 64; ++k) { P[k] = (k == l) ? 1.f : 0.f; U[k] = 0.f; }
  // pipeline registers: cur = step t, nxt = step t+1 (a is consumed from nxt)
  float w_c = bf2f(wb[base]);
  float v_c = bf2f(vb[base]);
  float r_c = bf2f(rb[base]);
  unsigned int bk_c = bk[base];
  float w_n = bf2f(wb[base + C_]);
  float v_n = bf2f(vb[base + C_]);
  float r_n = bf2f(rb[base + C_]);
  unsigned int bk_n = bk[base + C_];
  float a_n = bf2f(ab[base + C_]);     // a_{t+1} for t=0
  float saP = bf2f(ab[base]);          // t=0: A=I -> saP = a_0[l] (lane-local)
  float saU = 0.f;
  size_t obase = base;
  size_t zoff = zbase + l;
#pragma unroll 1
  for (int t = 0; t < L_; ++t) {
    int tf = t + 2; if (tf > L_ - 1) tf = L_ - 1;  // clamped value only feeds discarded sa_L
    size_t af = base + (size_t)tf * C_;
    float w_f = bf2f(wb[af]);
    float v_f = bf2f(vb[af]);
    float r_f = bf2f(rb[af]);
    unsigned int bk_f = bk[af];
    float a_f = bf2f(ab[af]);
    float ew = exp2f(w_c * 1.4426950408889634f);
    float vl = v_c, rl_ = r_c, al = a_n;
    float zz0 = 0.f, zz1 = 0.f, zz2 = 0.f, zz3 = 0.f;
    float yy0 = 0.f, yy1 = 0.f, yy2 = 0.f, yy3 = 0.f;
    float qp0 = 0.f, qp1 = 0.f, qp2 = 0.f, qp3 = 0.f;
    float qu0 = 0.f, qu1 = 0.f, qu2 = 0.f, qu3 = 0.f;
#pragma unroll
    for (int k = 0; k < 64; k += 4) {
#define STEPK(kk, ZZ, YY, QP, QU)                                        \
      {                                                                  \
        float s_ew = rlane(ew, kk);                                      \
        unsigned int u_bk =                                              \
            (unsigned int)__builtin_amdgcn_readlane((int)bk_c, kk);      \
        float s_b = uaf(u_bk << 16);                                     \
        float s_k = uaf(u_bk & 0xffff0000u);                             \
        float Pn = fmaf(P[kk], s_ew, s_b * saP);                         \
        float Un = fmaf(U[kk], s_ew, fmaf(s_b, saU, s_k * vl));          \
        P[kk] = Pn; U[kk] = Un;                                          \
        float s_r = rlane(rl_, kk), s_a = rlane(al, kk);                 \
        ZZ = fmaf(s_r, Pn, ZZ); YY = fmaf(s_r, Un, YY);                  \
        QP = fmaf(s_a, Pn, QP); QU = fmaf(s_a, Un, QU);                  \
      }
      STEPK(k,     zz0, yy0, qp0, qu0)
      STEPK(k + 1, zz1, yy1, qp1, qu1)
      STEPK(k + 2, zz2, yy2, qp2, qu2)
      STEPK(k + 3, zz3, yy3, qp3, qu3)
#undef STEPK
    }
    o[obase] = (yy0 + yy1) + (yy2 + yy3);
    Zg[zoff] = f2bf((zz0 + zz1) + (zz2 + zz3));
    saP = (qp0 + qp1) + (qp2 + qp3);
    saU = (qu0 + qu1) + (qu2 + qu3);
    obase += C_;
    zoff += 64;
    // rotate pipeline
    w_c = w_n; v_c = v_n; r_c = r_n; bk_c = bk_n;
    w_n = w_f; v_n = v_f; r_n = r_f; bk_n = bk_f;
    a_n = a_f;
  }
  size_t pb_ = (size_t)blk * 4096;
#pragma unroll
  for (int k4 = 0; k4 < 64; k4 += 4) {
    us4 pk4;
    pk4.x = f2bf(P[k4]); pk4.y = f2bf(P[k4 + 1]);
    pk4.z = f2bf(P[k4 + 2]); pk4.w = f2bf(P[k4 + 3]);
    *(us4*)(Pg + pb_ + (size_t)l * 64 + k4) = pk4;
  }
#pragma unroll
  for (int k = 0; k < 64; ++k) Ug[pb_ + (size_t)k * 64 + l] = U[k];
}

// ---------------- chunk combine: column-parallel (4 blocks per bh) ----------------
__global__ __launch_bounds__(256) void k_scanC(
    const unsigned short* __restrict__ Pg, const float* __restrict__ Ug,
    const float* __restrict__ s0, float* __restrict__ Scg, float* __restrict__ sout) {
  const int bh = blockIdx.x >> 2, q = blockIdx.x & 3;
  const int tid = threadIdx.x;
  const int col = tid & 15;
  const int r0 = (tid >> 4) * 4;
  const int colg = q * 16 + col;
  __shared__ float Sb[64][16];
  __shared__ alignas(16) unsigned short Pb[4096];
  float sreg[4];
#pragma unroll
  for (int rr = 0; rr < 4; ++rr) {
    float v = s0[(size_t)bh * 4096 + (r0 + rr) * 64 + colg];
    sreg[rr] = v; Sb[r0 + rr][col] = v;
  }
  {
    size_t cb0 = ((size_t)bh * NC_) * 4096;
    *(us4*)(Pb + tid * 16)      = *(const us4*)(Pg + cb0 + tid * 16);
    *(us4*)(Pb + tid * 16 + 4)  = *(const us4*)(Pg + cb0 + tid * 16 + 4);
    *(us4*)(Pb + tid * 16 + 8)  = *(const us4*)(Pg + cb0 + tid * 16 + 8);
    *(us4*)(Pb + tid * 16 + 12) = *(const us4*)(Pg + cb0 + tid * 16 + 12);
  }
  __syncthreads();
  for (int c = 0; c < NC_; ++c) {
    size_t cb = ((size_t)bh * NC_ + c) * 4096;
#pragma unroll
    for (int rr = 0; rr < 4; ++rr)
      Scg[cb + (size_t)(r0 + rr) * 64 + colg] = sreg[rr];
    float acc0 = Ug[cb + (size_t)r0 * 64 + colg];
    float acc1 = Ug[cb + (size_t)(r0 + 1) * 64 + colg];
    float acc2 = Ug[cb + (size_t)(r0 + 2) * 64 + colg];
    float acc3 = Ug[cb + (size_t)(r0 + 3) * 64 + colg];
    for (int j = 0; j < 64; ++j) {
      float s = Sb[j][col];
      us4 p4 = *(const us4*)(Pb + j * 64 + r0);
      acc0 = fmaf(bf2f(p4.x), s, acc0);
      acc1 = fmaf(bf2f(p4.y), s, acc1);
      acc2 = fmaf(bf2f(p4.z), s, acc2);
      acc3 = fmaf(bf2f(p4.w), s, acc3);
    }
    __syncthreads();
    Sb[r0][col] = acc0; Sb[r0 + 1][col] = acc1;
    Sb[r0 + 2][col] = acc2; Sb[r0 + 3][col] = acc3;
    sreg[0] = acc0; sreg[1] = acc1; sreg[2] = acc2; sreg[3] = acc3;
    if (c + 1 < NC_) {
      size_t cbn = cb + 4096;
      *(us4*)(Pb + tid * 16)      = *(const us4*)(Pg + cbn + tid * 16);
      *(us4*)(Pb + tid * 16 + 4)  = *(const us4*)(Pg + cbn + tid * 16 + 4);
      *(us4*)(Pb + tid * 16 + 8)  = *(const us4*)(Pg + cbn + tid * 16 + 8);
      *(us4*)(Pb + tid * 16 + 12) = *(const us4*)(Pg + cbn + tid * 16 + 12);
    }
    __syncthreads();
  }
#pragma unroll
  for (int rr = 0; rr < 4; ++rr)
    sout[(size_t)bh * 4096 + (r0 + rr) * 64 + colg] = sreg[rr];
}

// ---------------- apply chunk-start state: o += Z @ S0 (per chunk) ----------------
__global__ __launch_bounds__(256) void k_scanO(
    const unsigned short* __restrict__ Zg, const float* __restrict__ Scg,
    float* __restrict__ o) {
  const int blk = blockIdx.x;
  const int c = blk & (NC_ - 1), bh = blk / NC_;
  const int b = bh >> 5, h = bh & (H_ - 1);
  const int l = threadIdx.x & 63;
  const int w = threadIdx.x >> 6;
  float S[64];
  const float* Sp = Scg + (size_t)blk * 4096 + l;
#pragma unroll
  for (int k = 0; k < 64; ++k) S[k] = Sp[(size_t)k * 64];
  size_t zb = (size_t)blk * (L_ * 64);
  size_t ob = (size_t)b * ((size_t)T_ * C_) + (size_t)(c * L_) * C_ + h * 64 + l;
  for (int tt = 0; tt < L_ / 4; ++tt) {
    int t = w * (L_ / 4) + tt;
    float zv = bf2f(Zg[zb + t * 64 + l]);  // lane l holds z_t[l]
    float a0_ = 0.f, a1_ = 0.f, a2_ = 0.f, a3_ = 0.f;
#pragma unroll
    for (int k = 0; k < 64; k += 4) {
      a0_ = fmaf(rlane(zv, k), S[k], a0_);
      a1_ = fmaf(rlane(zv, k + 1), S[k + 1], a1_);
      a2_ = fmaf(rlane(zv, k + 2), S[k + 2], a2_);
      a3_ = fmaf(rlane(zv, k + 3), S[k + 3], a3_);
    }
    o[ob + (size_t)t * C_] += (a0_ + a1_) + (a2_ + a3_);
  }
}

// ---------------- post-scan: GroupNorm + bonus + *g (bf16) -> bf16 ----------------
__global__ __launch_bounds__(256) void k_post(
    const float* __restrict__ o, const float* __restrict__ vp,
    const unsigned short* __restrict__ gp,
    const float* __restrict__ dp,
    const float* __restrict__ lnw, const float* __restrict__ lnb,
    unsigned short* __restrict__ z) {
  int gw = blockIdx.x * 4 + (threadIdx.x >> 6);
  int l = threadIdx.x & 63;
  int h = gw & (H_ - 1);
  size_t bt = (size_t)(gw >> 5);
  size_t idx = bt * C_ + h * 64 + l;
  int c = h * 64 + l;
  float ov = o[idx];
  float s1 = ov;
#pragma unroll
  for (int m = 1; m < 64; m <<= 1) s1 += __shfl_xor(s1, m);
  float mu = s1 * (1.f / 64.f);
  float d = ov - mu;
  float s2 = d * d;
#pragma unroll
  for (int m = 1; m < 64; m <<= 1) s2 += __shfl_xor(s2, m);
  float var = s2 * (1.f / 64.f);
  float y = d * rsqrtf(var + 6.4e-4f);
  y = y * lnw[c] + lnb[c];
  y = fmaf(dp[bt * H_ + h], vp[idx], y);
  z[idx] = f2bf(y * bf2f(gp[idx]));
}

extern "C" void kernel_launch(void* const* d_in, const int* in_sizes, int n_in,
                              void* d_out, int out_size, void* d_ws, size_t ws_size,
                              hipStream_t stream) {
  const float* x      = (const float*)d_in[0];
  const float* shift  = (const float*)d_in[1];
  const float* wkv    = (const float*)d_in[2];
  const float* vfirst = (const float*)d_in[3];
  const float* x_r    = (const float*)d_in[4];
  const float* x_w    = (const float*)d_in[5];
  const float* x_k    = (const float*)d_in[6];
  const float* x_v    = (const float*)d_in[7];
  const float* x_a    = (const float*)d_in[8];
  const float* x_g    = (const float*)d_in[9];
  const float* w0     = (const float*)d_in[10];
  const float* w1     = (const float*)d_in[11];
  const float* w2     = (const float*)d_in[12];
  const float* a0     = (const float*)d_in[13];
  const float* a1     = (const float*)d_in[14];
  const float* a2     = (const float*)d_in[15];
  const float* v0     = (const float*)d_in[16];
  const float* v1     = (const float*)d_in[17];
  const float* v2     = (const float*)d_in[18];
  const float* g1     = (const float*)d_in[19];
  const float* g2     = (const float*)d_in[20];
  const float* k_k    = (const float*)d_in[21];
  const float* k_a    = (const float*)d_in[22];
  const float* r_k    = (const float*)d_in[23];
  const float* W_r    = (const float*)d_in[24];
  const float* W_k    = (const float*)d_in[25];
  const float* W_v    = (const float*)d_in[26];
  const float* W_o    = (const float*)d_in[27];
  const float* ln_w   = (const float*)d_in[28];
  const float* ln_b   = (const float*)d_in[29];

  // ---- workspace plan: ~213 MiB (footprint identical to passing version) ----
  char* wp = (char*)d_ws;
  auto alloc = [&](size_t bytes) { char* p = wp; wp += (bytes + 255) & ~(size_t)255; return p; };
  const size_t SB = BTC_ * 2;
  const size_t SF = BTC_ * 4;

  unsigned short* w1t = (unsigned short*)alloc((size_t)C_ * 64 * 2);
  unsigned short* w2t = (unsigned short*)alloc((size_t)C_ * 64 * 2);
  unsigned short* a1t = (unsigned short*)alloc((size_t)C_ * 64 * 2);
  unsigned short* a2t = (unsigned short*)alloc((size_t)C_ * 64 * 2);
  unsigned short* v1t = (unsigned short*)alloc((size_t)C_ * 32 * 2);
  unsigned short* v2t = (unsigned short*)alloc((size_t)C_ * 32 * 2);
  unsigned short* g1t = (unsigned short*)alloc((size_t)C_ * 128 * 2);
  unsigned short* g2t = (unsigned short*)alloc((size_t)C_ * 128 * 2);
  unsigned short* hw  = (unsigned short*)alloc((size_t)BT_ * 64 * 2);
  unsigned short* ha  = (unsigned short*)alloc((size_t)BT_ * 64 * 2);
  unsigned short* hv  = (unsigned short*)alloc((size_t)BT_ * 32 * 2);
  unsigned short* hg  = (unsigned short*)alloc((size_t)BT_ * 128 * 2);
  unsigned short* Wt2 = (unsigned short*)alloc((size_t)C_ * C_ * 2 * 2); // hi|lo; later Zg (bf16)
  float* dp           = (float*)alloc((size_t)BT_ * H_ * 4);
  unsigned short* xw  = (unsigned short*)alloc(SB);      // mix-w -> wb -> Scg lo half (f32)
  unsigned short* xa  = (unsigned short*)alloc(SB);      // mix-a -> ab -> Scg hi half
  unsigned short* xg  = (unsigned short*)alloc(SB);      // mix-g -> hv out -> rb (bf16)
  unsigned short* xr2 = (unsigned short*)alloc(2 * SB); // -> kbuf f32 -> Ug (f32) -> zbuf
  unsigned short* xk2 = (unsigned short*)alloc(2 * SB); // -> vbuf f32
  unsigned short* xv2 = (unsigned short*)alloc(2 * SB); // -> bk packed u32
  float* rbuf         = (float*)alloc(SF);              // r f32 -> g bf16 | Pg bf16
  unsigned short* vbb = (unsigned short*)alloc(SB);

  unsigned short* Wh = Wt2;
  unsigned short* Wl = Wt2 + (size_t)C_ * C_;
  unsigned short* xr_h = xr2, *xr_l = xr2 + BTC_;
  unsigned short* xk_h = xk2, *xk_l = xk2 + BTC_;
  unsigned short* xv_h = xv2, *xv_l = xv2 + BTC_;
  float* kbuf = (float*)xr2;
  float* vbuf = (float*)xk2;
  unsigned int* bkp = (unsigned int*)xv2;                  // packed k|b u32 (32MB)
  unsigned short* gb16 = (unsigned short*)rbuf;            // g bf16 (first half of rbuf)
  unsigned short* Pgb  = (unsigned short*)rbuf + BTC_;     // P bf16 (second half of rbuf)
  float* Ugf = (float*)xr2;                                // U f32 (fills xr2 at NC_=32)
  unsigned short* zbuf = (unsigned short*)xr2;             // k_post out (Ug dead by then)
  unsigned short* zg = Wt2;                                // z bf16 (Wt2 dead here)
  float* Scg = (float*)xw;                                 // chunk-start states, spans xw+xa

  float* outp  = (float*)d_out;
  float* xlast = outp + BTC_;
  float* soutp = outp + BTC_ + (size_t)B_ * C_;
  float* obuf  = outp;

  auto tr = [&](const float* in, unsigned short* out, int R, int Cc) {
    k_tr<<<dim3(Cc / 32, R / 32), 256, 0, stream>>>(in, out, R, Cc);
  };
  auto gemm = [&](const unsigned short* X, const unsigned short* Wtp, void* out,
                  int M, int N, int K, int mode) {
    k_gemm<<<dim3((N + 127) / 128, M / 128), 256, 0, stream>>>(X, Wtp, out, M, N, K, mode);
  };
  auto gemm2 = [&](const unsigned short* Xh_, const unsigned short* Xl_, int xlo,
                   const unsigned short* Wh_, const unsigned short* Wl_, int wlo,
                   void* out, int M, int N, int K, int mode) {
    k_gemm2<<<dim3((N + 127) / 128, M / 128), 256, 0, stream>>>(Xh_, Xl_, xlo, Wh_, Wl_, wlo,
                                                                out, M, N, K, mode);
  };

  k_mix<<<(int)(BTC_ / 4 / 256), 256, 0, stream>>>(x, shift, x_r, x_w, x_k, x_v, x_a, x_g,
                                                   xr_h, xr_l, xk_h, xk_l, xv_h, xv_l,
                                                   xw, xa, xg, xlast);
  tr(w1, w1t, C_, 64);  tr(w2, w2t, 64, C_);
  tr(a1, a1t, C_, 64);  tr(a2, a2t, 64, C_);
  tr(v1, v1t, C_, 32);  tr(v2, v2t, 32, C_);
  tr(g1, g1t, C_, 128); tr(g2, g2t, 128, C_);

  // LoRA stage 1
  gemm(xw, w1t, hw, BT_, 64, C_, 2);
  gemm(xa, a1t, ha, BT_, 64, C_, 1);
  gemm2(xv_h, xv_l, 1, v1t, nullptr, 0, hv, BT_, 32, C_, 1);
  gemm(xg, g1t, hg, BT_, 128, C_, 3);

  // big projections, split precision (hh + lh + hl)
  k_trs<<<dim3(C_ / 32, C_ / 32), 256, 0, stream>>>(W_r, Wh, Wl, C_, C_);
  gemm2(xr_h, xr_l, 1, Wh, Wl, 1, rbuf, BT_, C_, C_, 0);
  k_trs<<<dim3(C_ / 32, C_ / 32), 256, 0, stream>>>(W_k, Wh, Wl, C_, C_);
  gemm2(xk_h, xk_l, 1, Wh, Wl, 1, kbuf, BT_, C_, C_, 0);
  k_trs<<<dim3(C_ / 32, C_ / 32), 256, 0, stream>>>(W_v, Wh, Wl, C_, C_);
  gemm2(xv_h, xv_l, 1, Wh, Wl, 1, vbuf, BT_, C_, C_, 0);

  // LoRA stage 2 into dead mix buffers
  gemm(hw, w2t, xw, BT_, C_, 64, 1);
  gemm(ha, a2t, xa, BT_, C_, 64, 1);
  gemm(hv, v2t, xg, BT_, C_, 32, 1);

  k_pre<<<BT_ * H_ / 4, 256, 0, stream>>>(rbuf, kbuf, vbuf, xw, xa, xg, vfirst,
                                          w0, a0, v0, k_k, k_a, r_k,
                                          xw, xa, xg, vbb, bkp, dp);

  // g in bf16 (r dead; first half of rbuf)
  gemm(hg, g2t, gb16, BT_, C_, 128, 1);

  // chunk-parallel scan: P/U/z/y in one pass, column-parallel combine, apply S0
  k_scanP<<<B_ * H_ * NC_, 64, 0, stream>>>(xw, xa, xg, vbb, bkp, Pgb, Ugf, zg, obuf);
  k_scanC<<<B_ * H_ * 4, 256, 0, stream>>>(Pgb, Ugf, wkv, Scg, soutp);
  k_scanO<<<B_ * H_ * NC_, 256, 0, stream>>>(zg, Scg, obuf);

  k_post<<<BT_ * H_ / 4, 256, 0, stream>>>(obuf, vbuf, gb16, dp, ln_w, ln_b, zbuf);

  tr(W_o, Wh, C_, C_);
  gemm(zbuf, Wh, outp, BT_, C_, C_, 0);
}